// Round 1
// baseline (3945.187 us; speedup 1.0000x reference)
//
#include <hip/hip_runtime.h>

#define N_NODES 50000
#define N_EDGES 800000

// ---------- helpers: order-preserving float<->uint encoding for atomicMax ----------
__device__ __forceinline__ unsigned enc_f(float f) {
    unsigned u = __float_as_uint(f);
    return (u & 0x80000000u) ? ~u : (u | 0x80000000u);
}
__device__ __forceinline__ float dec_f(unsigned u) {
    return (u & 0x80000000u) ? __uint_as_float(u & 0x7fffffffu) : __uint_as_float(~u);
}

// ---------- GEMM: h[N,Fout] = x[N,Fin] @ W[Fin,Fout] ----------
// One block computes ROWS rows; x rows staged in LDS; W streamed (L2-resident).
template <int ROWS>
__global__ void gemm_rows(const float* __restrict__ x, const float* __restrict__ W,
                          float* __restrict__ h, int Fin, int Fout) {
    extern __shared__ float xs[];  // ROWS * Fin
    const int r0 = blockIdx.x * ROWS;
    const int c  = threadIdx.x;    // c < Fout (blockDim.x == Fout)
    for (int r = 0; r < ROWS; ++r) {
        int rr = r0 + r;
        for (int k = threadIdx.x; k < Fin; k += blockDim.x)
            xs[r * Fin + k] = (rr < N_NODES) ? x[(long long)rr * Fin + k] : 0.f;
    }
    __syncthreads();
    float acc[ROWS];
#pragma unroll
    for (int i = 0; i < ROWS; ++i) acc[i] = 0.f;
    for (int k = 0; k < Fin; ++k) {
        float w = W[k * Fout + c];
#pragma unroll
        for (int i = 0; i < ROWS; ++i) acc[i] += xs[i * Fin + k] * w;
    }
#pragma unroll
    for (int i = 0; i < ROWS; ++i) {
        int rr = r0 + i;
        if (rr < N_NODES) h[(long long)rr * Fout + c] = acc[i];
    }
}

// ---------- per-node attention logits: el[n,h] = sum_d h[n,h,d]*al[h,d] ----------
__global__ void eler_kernel(const float* __restrict__ h, const float* __restrict__ al,
                            const float* __restrict__ ar, float* __restrict__ el,
                            float* __restrict__ er, int H, int D) {
    const int Fout = H * D;
    __shared__ float sl[128], sr[128];
    const int n = blockIdx.x;
    const int t = threadIdx.x;  // t < Fout
    float v = h[(long long)n * Fout + t];
    sl[t] = v * al[t];
    sr[t] = v * ar[t];
    __syncthreads();
    if (t < H) {
        float a = 0.f, b = 0.f;
        for (int d = 0; d < D; ++d) { a += sl[t * D + d]; b += sr[t * D + d]; }
        el[n * H + t] = a;
        er[n * H + t] = b;
    }
}

// ---------- init per-layer accumulators ----------
__global__ void init_layer(unsigned* __restrict__ m_enc, float* __restrict__ denom,
                           float* __restrict__ outb, int NH, int NF) {
    int i = blockIdx.x * blockDim.x + threadIdx.x;
    if (i < NH) { m_enc[i] = 0u; denom[i] = 0.f; }  // 0 < enc(any float) => acts as -inf
    if (i < NF) outb[i] = 0.f;
}

// ---------- edge pass A: e = leakyrelu(el[src]+er[dst]); segment max into m ----------
__global__ void edge_max(const int* __restrict__ src, const int* __restrict__ dst,
                         const float* __restrict__ el, const float* __restrict__ er,
                         float* __restrict__ ebuf, unsigned* __restrict__ m_enc, int H) {
    long long tid = (long long)blockIdx.x * blockDim.x + threadIdx.x;
    if (tid >= (long long)N_EDGES * H) return;
    int h = (int)(tid % H);
    int e = (int)(tid / H);
    int s = src[e], d = dst[e];
    float v = el[s * H + h] + er[d * H + h];
    v = (v >= 0.f) ? v : 0.2f * v;
    ebuf[tid] = v;
    atomicMax(m_enc + (d * H + h), enc_f(v));
}

// ---------- edge pass B: ex = exp(e - m[dst]); segment sum into denom ----------
__global__ void edge_expsum(const int* __restrict__ dst, const unsigned* __restrict__ m_enc,
                            float* __restrict__ ebuf, float* __restrict__ denom, int H) {
    long long tid = (long long)blockIdx.x * blockDim.x + threadIdx.x;
    if (tid >= (long long)N_EDGES * H) return;
    int h = (int)(tid % H);
    int e = (int)(tid / H);
    int d = dst[e];
    float m  = dec_f(m_enc[d * H + h]);
    float ex = expf(ebuf[tid] - m);
    ebuf[tid] = ex;  // overwrite with numerator
    atomicAdd(denom + (d * H + h), ex);
}

// ---------- edge pass C: out[dst] += (ex/denom[dst]) * h[src] ----------
// TPE threads per edge, each thread does one float4 slice of the Fout dims.
__global__ void edge_aggregate(const int* __restrict__ src, const int* __restrict__ dst,
                               const float* __restrict__ ebuf, const float* __restrict__ denom,
                               const float* __restrict__ h, float* __restrict__ outb,
                               int H, int D, int Fout, int TPE) {
    long long tid = (long long)blockIdx.x * blockDim.x + threadIdx.x;
    long long total = (long long)N_EDGES * TPE;
    if (tid >= total) return;
    int lane = (int)(tid % TPE);
    int e    = (int)(tid / TPE);
    int d0 = lane * 4;
    int hd = d0 / D;
    int s = src[e], dn = dst[e];
    float alpha = ebuf[(long long)e * H + hd] / denom[dn * H + hd];
    const float4 hv = *reinterpret_cast<const float4*>(h + (long long)s * Fout + d0);
    float* op = outb + (long long)dn * Fout + d0;
    atomicAdd(op + 0, alpha * hv.x);
    atomicAdd(op + 1, alpha * hv.y);
    atomicAdd(op + 2, alpha * hv.z);
    atomicAdd(op + 3, alpha * hv.w);
}

// ---------- finalize: add bias, optional relu ----------
__global__ void finalize_layer(const float* __restrict__ outb, const float* __restrict__ bias,
                               float* __restrict__ xnext, int Fout, int do_relu) {
    int i = blockIdx.x * blockDim.x + threadIdx.x;
    if (i >= N_NODES * Fout) return;
    int d = i % Fout;
    float v = outb[i] + bias[d];
    if (do_relu) v = fmaxf(v, 0.f);
    xnext[i] = v;
}

// ---------- host-side layer driver ----------
static void run_layer(const float* x, int Fin, const float* W, const float* al,
                      const float* ar, const float* bias, int H, int D,
                      const int* src, const int* dst,
                      float* h, float* el, float* er, unsigned* m_enc, float* denom,
                      float* ebuf, float* outb, float* xnext, int do_relu,
                      hipStream_t stream) {
    const int Fout = H * D;
    const int ROWS = 8;
    int gblocks = (N_NODES + ROWS - 1) / ROWS;
    gemm_rows<ROWS><<<gblocks, Fout, ROWS * Fin * (int)sizeof(float), stream>>>(x, W, h, Fin, Fout);
    eler_kernel<<<N_NODES, Fout, 0, stream>>>(h, al, ar, el, er, H, D);
    int NH = N_NODES * H, NF = N_NODES * Fout;
    init_layer<<<(NF + 255) / 256, 256, 0, stream>>>(m_enc, denom, outb, NH, NF);
    long long EH = (long long)N_EDGES * H;
    int eb = (int)((EH + 255) / 256);
    edge_max<<<eb, 256, 0, stream>>>(src, dst, el, er, ebuf, m_enc, H);
    edge_expsum<<<eb, 256, 0, stream>>>(dst, m_enc, ebuf, denom, H);
    int TPE = Fout / 4;
    long long ET = (long long)N_EDGES * TPE;
    edge_aggregate<<<(int)((ET + 255) / 256), 256, 0, stream>>>(src, dst, ebuf, denom, h, outb,
                                                               H, D, Fout, TPE);
    finalize_layer<<<(NF + 255) / 256, 256, 0, stream>>>(outb, bias, xnext, Fout, do_relu);
}

extern "C" void kernel_launch(void* const* d_in, const int* in_sizes, int n_in,
                              void* d_out, int out_size, void* d_ws, size_t ws_size,
                              hipStream_t stream) {
    const float* feat = (const float*)d_in[0];
    const int*   src  = (const int*)d_in[1];
    const int*   dst  = (const int*)d_in[2];
    const float* W1  = (const float*)d_in[3];
    const float* al1 = (const float*)d_in[4];
    const float* ar1 = (const float*)d_in[5];
    const float* b1  = (const float*)d_in[6];
    const float* W2  = (const float*)d_in[7];
    const float* al2 = (const float*)d_in[8];
    const float* ar2 = (const float*)d_in[9];
    const float* b2  = (const float*)d_in[10];
    const float* W3  = (const float*)d_in[11];
    const float* al3 = (const float*)d_in[12];
    const float* ar3 = (const float*)d_in[13];
    const float* b3  = (const float*)d_in[14];

    // workspace carve-up (all f32-sized slots, 4-byte aligned)
    float* ws = (float*)d_ws;
    float*    h     = ws;                          // N*128
    float*    xbuf  = h    + (long long)N_NODES * 128;  // N*128
    float*    outb  = xbuf + (long long)N_NODES * 128;  // N*128
    float*    el    = outb + (long long)N_NODES * 128;  // N*4
    float*    er    = el   + (long long)N_NODES * 4;    // N*4
    unsigned* m_enc = (unsigned*)(er + (long long)N_NODES * 4);  // N*4
    float*    denom = (float*)(m_enc + (long long)N_NODES * 4);  // N*4
    float*    ebuf  = denom + (long long)N_NODES * 4;   // E*4

    // layer 1: 256 -> 4x32, relu
    run_layer(feat, 256, W1, al1, ar1, b1, 4, 32, src, dst,
              h, el, er, m_enc, denom, ebuf, outb, xbuf, 1, stream);
    // layer 2: 128 -> 4x32, relu
    run_layer(xbuf, 128, W2, al2, ar2, b2, 4, 32, src, dst,
              h, el, er, m_enc, denom, ebuf, outb, xbuf, 1, stream);
    // layer 3: 128 -> 1x64, no relu, straight to d_out
    run_layer(xbuf, 128, W3, al3, ar3, b3, 1, 64, src, dst,
              h, el, er, m_enc, denom, ebuf, outb, (float*)d_out, 0, stream);
}

// Round 2
// 656.554 us; speedup vs baseline: 6.0089x; 6.0089x over previous
//
#include <hip/hip_runtime.h>
#include <cfloat>

#define N_NODES 50000
#define N_EDGES 800000

// ============================================================================
// GEMM: h[N,Fout] = x[N,Fin] @ W[Fin,Fout]
// One block computes ROWS rows; x rows staged in LDS; W streamed (L2-resident).
// ============================================================================
template <int ROWS>
__global__ void gemm_rows(const float* __restrict__ x, const float* __restrict__ W,
                          float* __restrict__ h, int Fin, int Fout) {
    extern __shared__ float xs[];  // ROWS * Fin
    const int r0 = blockIdx.x * ROWS;
    const int c  = threadIdx.x;    // c < Fout (blockDim.x == Fout)
    for (int r = 0; r < ROWS; ++r) {
        int rr = r0 + r;
        for (int k = threadIdx.x; k < Fin; k += blockDim.x)
            xs[r * Fin + k] = (rr < N_NODES) ? x[(long long)rr * Fin + k] : 0.f;
    }
    __syncthreads();
    float acc[ROWS];
#pragma unroll
    for (int i = 0; i < ROWS; ++i) acc[i] = 0.f;
    for (int k = 0; k < Fin; ++k) {
        float w = W[k * Fout + c];
#pragma unroll
        for (int i = 0; i < ROWS; ++i) acc[i] += xs[i * Fin + k] * w;
    }
#pragma unroll
    for (int i = 0; i < ROWS; ++i) {
        int rr = r0 + i;
        if (rr < N_NODES) h[(long long)rr * Fout + c] = acc[i];
    }
}

// ============================================================================
// per-node attention logits: el[n,h] = sum_d h[n,h,d]*al[h,d]  (same for er)
// ============================================================================
__global__ void eler_kernel(const float* __restrict__ h, const float* __restrict__ al,
                            const float* __restrict__ ar, float* __restrict__ el,
                            float* __restrict__ er, int H, int D) {
    const int Fout = H * D;
    __shared__ float sl[128], sr[128];
    const int n = blockIdx.x;
    const int t = threadIdx.x;  // t < Fout
    float v = h[(long long)n * Fout + t];
    sl[t] = v * al[t];
    sr[t] = v * ar[t];
    __syncthreads();
    if (t < H) {
        float a = 0.f, b = 0.f;
        for (int d = 0; d < D; ++d) { a += sl[t * D + d]; b += sr[t * D + d]; }
        el[n * H + t] = a;
        er[n * H + t] = b;
    }
}

// ============================================================================
// CSR build (once per call; graph shared by all 3 layers)
// ============================================================================
__global__ void zero_counts(int* __restrict__ counts) {
    int i = blockIdx.x * blockDim.x + threadIdx.x;
    if (i < N_NODES) counts[i] = 0;
}

__global__ void hist_kernel(const int* __restrict__ dst, int* __restrict__ counts) {
    int e = blockIdx.x * blockDim.x + threadIdx.x;
    if (e < N_EDGES) atomicAdd(counts + dst[e], 1);
}

// single-block exclusive scan over N_NODES; writes row_ptr[0..N] and cursor copy
__global__ void scan_kernel(const int* __restrict__ counts, int* __restrict__ row_ptr,
                            int* __restrict__ cursor) {
    __shared__ int tmp[1024];
    __shared__ int carry_s;
    const int tid = threadIdx.x;
    if (tid == 0) carry_s = 0;
    __syncthreads();
    for (int base = 0; base < N_NODES; base += 1024) {
        int i = base + tid;
        int v = (i < N_NODES) ? counts[i] : 0;
        tmp[tid] = v;
        __syncthreads();
        for (int off = 1; off < 1024; off <<= 1) {
            int t = (tid >= off) ? tmp[tid - off] : 0;
            __syncthreads();
            tmp[tid] += t;
            __syncthreads();
        }
        int excl = tmp[tid] - v + carry_s;
        if (i < N_NODES) { row_ptr[i] = excl; cursor[i] = excl; }
        __syncthreads();
        if (tid == 1023) carry_s += tmp[1023];
        __syncthreads();
    }
    if (tid == 0) row_ptr[N_NODES] = carry_s;
}

__global__ void scatter_kernel(const int* __restrict__ src, const int* __restrict__ dst,
                               int* __restrict__ cursor, int* __restrict__ sorted_src) {
    int e = blockIdx.x * blockDim.x + threadIdx.x;
    if (e >= N_EDGES) return;
    int pos = atomicAdd(cursor + dst[e], 1);
    sorted_src[pos] = src[e];
}

// ============================================================================
// Fused per-dst-node softmax + aggregate + bias (+relu).
// One block of H*D threads per node. No atomics, one write per output elem.
// ============================================================================
template <int H, int D>
__global__ void __launch_bounds__(H * D)
gat_aggregate_csr(const int* __restrict__ row_ptr, const int* __restrict__ sorted_src,
                  const float* __restrict__ el, const float* __restrict__ er,
                  const float* __restrict__ h, const float* __restrict__ bias,
                  float* __restrict__ out, int do_relu) {
    constexpr int F = H * D;
    constexpr int CHUNK = F / H;  // edges processed per phase-2 chunk
    const int n = blockIdx.x;
    const int t = threadIdx.x;

    __shared__ float er_n[H];
    __shared__ float rm[F], rs[F];
    __shared__ float sm_m[H], sm_inv[H];
    __shared__ int   s_src[CHUNK];
    __shared__ float s_w[CHUNK * H];

    const int start = row_ptr[n];
    const int deg   = row_ptr[n + 1] - start;

    if (t < H) er_n[t] = er[n * H + t];
    __syncthreads();

    // ---- phase 1: online softmax stats (m, s) per head ----
    const int ht1 = t % H;       // head this lane reduces
    float m = -FLT_MAX, s = 0.f;
    for (int ei = t / H; ei < deg; ei += CHUNK) {
        int ssrc = sorted_src[start + ei];
        float v = el[ssrc * H + ht1] + er_n[ht1];
        v = (v >= 0.f) ? v : 0.2f * v;
        float mn = fmaxf(m, v);
        s = s * expf(m - mn) + expf(v - mn);
        m = mn;
    }
    rm[t] = m; rs[t] = s;
    __syncthreads();
    for (int off = F / 2; off >= H; off >>= 1) {
        if (t < off) {
            float m2 = rm[t + off], s2 = rs[t + off];
            float mn = fmaxf(rm[t], m2);
            rs[t] = rs[t] * expf(rm[t] - mn) + s2 * expf(m2 - mn);
            rm[t] = mn;
        }
        __syncthreads();
    }
    if (t < H) {
        sm_m[t]   = rm[t];
        sm_inv[t] = (rs[t] > 0.f) ? 1.f / rs[t] : 0.f;
    }
    __syncthreads();

    // ---- phase 2: accumulate alpha * h[src] over edges, chunked ----
    const int ht2 = t / D;       // head of this output column
    const int d   = t % D;
    float acc = 0.f;
    for (int base = 0; base < deg; base += CHUNK) {
        int cnt = min(CHUNK, deg - base);
        if (t < cnt) s_src[t] = sorted_src[start + base + t];
        __syncthreads();
        {   // thread t computes weight for (edge ee = t/H, head t%H)
            int ee = t / H;
            if (ee < cnt) {
                int ssrc = s_src[ee];
                float v = el[ssrc * H + ht1] + er_n[ht1];
                v = (v >= 0.f) ? v : 0.2f * v;
                s_w[ee * H + ht1] = expf(v - sm_m[ht1]) * sm_inv[ht1];
            }
        }
        __syncthreads();
        for (int ee = 0; ee < cnt; ++ee) {
            acc += s_w[ee * H + ht2] * h[(long long)s_src[ee] * F + ht2 * D + d];
        }
        __syncthreads();
    }

    float o = acc + bias[t];
    if (do_relu) o = fmaxf(o, 0.f);
    out[(long long)n * F + t] = o;
}

// ============================================================================
// host-side layer driver
// ============================================================================
static void run_layer(const float* x, int Fin, const float* W, const float* al,
                      const float* ar, const float* bias, int H, int D,
                      const int* row_ptr, const int* sorted_src,
                      float* h, float* el, float* er, float* xnext, int do_relu,
                      hipStream_t stream) {
    const int Fout = H * D;
    const int ROWS = 8;
    int gblocks = (N_NODES + ROWS - 1) / ROWS;
    gemm_rows<ROWS><<<gblocks, Fout, ROWS * Fin * (int)sizeof(float), stream>>>(x, W, h, Fin, Fout);
    eler_kernel<<<N_NODES, Fout, 0, stream>>>(h, al, ar, el, er, H, D);
    if (H == 4) {
        gat_aggregate_csr<4, 32><<<N_NODES, 128, 0, stream>>>(row_ptr, sorted_src, el, er, h,
                                                              bias, xnext, do_relu);
    } else {
        gat_aggregate_csr<1, 64><<<N_NODES, 64, 0, stream>>>(row_ptr, sorted_src, el, er, h,
                                                             bias, xnext, do_relu);
    }
}

extern "C" void kernel_launch(void* const* d_in, const int* in_sizes, int n_in,
                              void* d_out, int out_size, void* d_ws, size_t ws_size,
                              hipStream_t stream) {
    const float* feat = (const float*)d_in[0];
    const int*   src  = (const int*)d_in[1];
    const int*   dst  = (const int*)d_in[2];
    const float* W1  = (const float*)d_in[3];
    const float* al1 = (const float*)d_in[4];
    const float* ar1 = (const float*)d_in[5];
    const float* b1  = (const float*)d_in[6];
    const float* W2  = (const float*)d_in[7];
    const float* al2 = (const float*)d_in[8];
    const float* ar2 = (const float*)d_in[9];
    const float* b2  = (const float*)d_in[10];
    const float* W3  = (const float*)d_in[11];
    const float* al3 = (const float*)d_in[12];
    const float* ar3 = (const float*)d_in[13];
    const float* b3  = (const float*)d_in[14];

    // workspace carve-up
    float* ws = (float*)d_ws;
    float* h    = ws;                                   // N*128
    float* xbuf = h    + (long long)N_NODES * 128;      // N*128
    float* el   = xbuf + (long long)N_NODES * 128;      // N*4
    float* er   = el   + (long long)N_NODES * 4;        // N*4
    int* counts     = (int*)(er + (long long)N_NODES * 4);  // N
    int* row_ptr    = counts  + N_NODES;                    // N+1
    int* cursor     = row_ptr + N_NODES + 1;                // N
    int* sorted_src = cursor  + N_NODES;                    // E

    // ---- build CSR once (graph shared by all 3 layers) ----
    zero_counts<<<(N_NODES + 255) / 256, 256, 0, stream>>>(counts);
    hist_kernel<<<(N_EDGES + 255) / 256, 256, 0, stream>>>(dst, counts);
    scan_kernel<<<1, 1024, 0, stream>>>(counts, row_ptr, cursor);
    scatter_kernel<<<(N_EDGES + 255) / 256, 256, 0, stream>>>(src, dst, cursor, sorted_src);

    // layer 1: 256 -> 4x32, relu
    run_layer(feat, 256, W1, al1, ar1, b1, 4, 32, row_ptr, sorted_src,
              h, el, er, xbuf, 1, stream);
    // layer 2: 128 -> 4x32, relu
    run_layer(xbuf, 128, W2, al2, ar2, b2, 4, 32, row_ptr, sorted_src,
              h, el, er, xbuf, 1, stream);
    // layer 3: 128 -> 1x64, no relu, straight to d_out
    run_layer(xbuf, 128, W3, al3, ar3, b3, 1, 64, row_ptr, sorted_src,
              h, el, er, (float*)d_out, 0, stream);
}

// Round 3
// 593.278 us; speedup vs baseline: 6.6498x; 1.1067x over previous
//
#include <hip/hip_runtime.h>
#include <cfloat>

#define N_NODES 50000
#define N_EDGES 800000

// ============================================================================
// Register-tiled GEMM: h[N,BN] = x[N,Fin] @ W[Fin,BN]   (BN = Fout = 128 or 64)
// BM=128 rows/block, BK=32, 256 threads, 8 rows x (8|4) cols per thread.
// x staged transposed in LDS (xs[k][row]) for float4 row-group reads.
// ============================================================================
template <int BN>
__global__ __launch_bounds__(256)
void gemm_tile(const float* __restrict__ x, const float* __restrict__ W,
               float* __restrict__ h, int Fin) {
    constexpr int BM = 128, BK = 32;
    constexpr int CN = (BN == 128) ? 8 : 4;       // cols per thread
    constexpr int NF = BN * BK / 256;             // W floats per thread (16|8)
    constexpr int NV = NF / 4;                    // float4s per thread (4|2)
    __shared__ float xs[BK][BM];
    __shared__ float ws[BK][BN];

    const int t  = threadIdx.x;
    const int r0 = blockIdx.x * BM;
    const int tr = t / 16, tc = t % 16;

    // x staging assignment: row = t/2, k-halfrange = (t%2)*16
    const int xrow  = t >> 1;
    const int xkoff = (t & 1) * 16;
    const bool xok  = (r0 + xrow) < N_NODES;
    const float* xrp = x + (long long)(r0 + xrow) * Fin;
    // W staging assignment: k-row = t/8, colbase = (t%8)*NF
    const int wk  = t >> 3;
    const int wcb = (t & 7) * NF;

    float acc[8][CN];
#pragma unroll
    for (int i = 0; i < 8; ++i)
#pragma unroll
        for (int j = 0; j < CN; ++j) acc[i][j] = 0.f;

    for (int k0 = 0; k0 < Fin; k0 += BK) {
        // ---- stage x (transposed) ----
#pragma unroll
        for (int j = 0; j < 4; ++j) {
            float4 v = make_float4(0.f, 0.f, 0.f, 0.f);
            if (xok) v = *reinterpret_cast<const float4*>(xrp + k0 + xkoff + 4 * j);
            xs[xkoff + 4 * j + 0][xrow] = v.x;
            xs[xkoff + 4 * j + 1][xrow] = v.y;
            xs[xkoff + 4 * j + 2][xrow] = v.z;
            xs[xkoff + 4 * j + 3][xrow] = v.w;
        }
        // ---- stage W ----
#pragma unroll
        for (int j = 0; j < NV; ++j) {
            float4 v = *reinterpret_cast<const float4*>(W + (long long)(k0 + wk) * BN + wcb + 4 * j);
            *reinterpret_cast<float4*>(&ws[wk][wcb + 4 * j]) = v;
        }
        __syncthreads();

#pragma unroll
        for (int kk = 0; kk < BK; ++kk) {
            float ra[8], rb[CN];
            float4 a0 = *reinterpret_cast<const float4*>(&xs[kk][tr * 4]);
            float4 a1 = *reinterpret_cast<const float4*>(&xs[kk][tr * 4 + 64]);
            ra[0] = a0.x; ra[1] = a0.y; ra[2] = a0.z; ra[3] = a0.w;
            ra[4] = a1.x; ra[5] = a1.y; ra[6] = a1.z; ra[7] = a1.w;
            float4 b0 = *reinterpret_cast<const float4*>(&ws[kk][tc * 4]);
            rb[0] = b0.x; rb[1] = b0.y; rb[2] = b0.z; rb[3] = b0.w;
            if (BN == 128) {
                float4 b1 = *reinterpret_cast<const float4*>(&ws[kk][tc * 4 + 64]);
                rb[4] = b1.x; rb[5] = b1.y; rb[6] = b1.z; rb[7] = b1.w;
            }
#pragma unroll
            for (int i = 0; i < 8; ++i)
#pragma unroll
                for (int j = 0; j < CN; ++j) acc[i][j] += ra[i] * rb[j];
        }
        __syncthreads();
    }

    // ---- epilogue ----
#pragma unroll
    for (int i = 0; i < 8; ++i) {
        int row = r0 + tr * 4 + (i / 4) * 64 + (i % 4);
        if (row < N_NODES) {
            float4 v0 = make_float4(acc[i][0], acc[i][1], acc[i][2], acc[i][3]);
            *reinterpret_cast<float4*>(h + (long long)row * BN + tc * 4) = v0;
            if (BN == 128) {
                float4 v1 = make_float4(acc[i][4], acc[i][5], acc[i][6], acc[i][7]);
                *reinterpret_cast<float4*>(h + (long long)row * BN + tc * 4 + 64) = v1;
            }
        }
    }
}

// ============================================================================
// per-node attention logits: el[n,h] = sum_d h[n,h,d]*al[h,d]  (same for er)
// ============================================================================
__global__ void eler_kernel(const float* __restrict__ h, const float* __restrict__ al,
                            const float* __restrict__ ar, float* __restrict__ el,
                            float* __restrict__ er, int H, int D) {
    const int Fout = H * D;
    __shared__ float sl[128], sr[128];
    const int n = blockIdx.x;
    const int t = threadIdx.x;  // t < Fout
    float v = h[(long long)n * Fout + t];
    sl[t] = v * al[t];
    sr[t] = v * ar[t];
    __syncthreads();
    if (t < H) {
        float a = 0.f, b = 0.f;
        for (int d = 0; d < D; ++d) { a += sl[t * D + d]; b += sr[t * D + d]; }
        el[n * H + t] = a;
        er[n * H + t] = b;
    }
}

// ============================================================================
// CSR build (once per call; graph shared by all 3 layers)
// ============================================================================
__global__ void zero_counts(int* __restrict__ counts) {
    int i = blockIdx.x * blockDim.x + threadIdx.x;
    if (i < N_NODES) counts[i] = 0;
}

__global__ void hist_kernel(const int* __restrict__ dst, int* __restrict__ counts) {
    int e = blockIdx.x * blockDim.x + threadIdx.x;
    if (e < N_EDGES) atomicAdd(counts + dst[e], 1);
}

__global__ void scan_kernel(const int* __restrict__ counts, int* __restrict__ row_ptr,
                            int* __restrict__ cursor) {
    __shared__ int tmp[1024];
    __shared__ int carry_s;
    const int tid = threadIdx.x;
    if (tid == 0) carry_s = 0;
    __syncthreads();
    for (int base = 0; base < N_NODES; base += 1024) {
        int i = base + tid;
        int v = (i < N_NODES) ? counts[i] : 0;
        tmp[tid] = v;
        __syncthreads();
        for (int off = 1; off < 1024; off <<= 1) {
            int t = (tid >= off) ? tmp[tid - off] : 0;
            __syncthreads();
            tmp[tid] += t;
            __syncthreads();
        }
        int excl = tmp[tid] - v + carry_s;
        if (i < N_NODES) { row_ptr[i] = excl; cursor[i] = excl; }
        __syncthreads();
        if (tid == 1023) carry_s += tmp[1023];
        __syncthreads();
    }
    if (tid == 0) row_ptr[N_NODES] = carry_s;
}

__global__ void scatter_kernel(const int* __restrict__ src, const int* __restrict__ dst,
                               int* __restrict__ cursor, int* __restrict__ sorted_src) {
    int e = blockIdx.x * blockDim.x + threadIdx.x;
    if (e >= N_EDGES) return;
    int pos = atomicAdd(cursor + dst[e], 1);
    sorted_src[pos] = src[e];
}

// ============================================================================
// Wave-per-node fused softmax + aggregate + bias (+relu). 4 waves/block,
// no block barriers, shfl-only reductions, one write per output element.
// ============================================================================
template <int H, int D>
__global__ __launch_bounds__(256)
void gat_aggregate_wave(const int* __restrict__ row_ptr, const int* __restrict__ sorted_src,
                        const float* __restrict__ el, const float* __restrict__ er,
                        const float* __restrict__ h, const float* __restrict__ bias,
                        float* __restrict__ out, int do_relu) {
    constexpr int F   = H * D;
    constexpr int CPL = F / 64;   // cols per lane: 2 (F=128) or 1 (F=64)
    const int lane = threadIdx.x & 63;
    const int wid  = threadIdx.x >> 6;
    const int n    = blockIdx.x * 4 + wid;
    if (n >= N_NODES) return;

    const int start = row_ptr[n];
    const int deg   = row_ptr[n + 1] - start;

    // ---- phase 1: online softmax stats, lane handles head h1, edge-slot lane/H ----
    const int h1 = lane % H;
    const float er1 = er[n * H + h1];
    float m = -FLT_MAX, s = 0.f;
    for (int ei = lane / H; ei < deg; ei += 64 / H) {
        int sr = sorted_src[start + ei];
        float v = el[sr * H + h1] + er1;
        v = (v >= 0.f) ? v : 0.2f * v;
        if (v > m) { s = s * expf(m - v) + 1.f; m = v; }
        else       { s += expf(v - m); }
    }
    // merge across lanes with the same head (xor strides H..32)
#pragma unroll
    for (int off = H; off < 64; off <<= 1) {
        float mo = __shfl_xor(m, off);
        float so = __shfl_xor(s, off);
        float mn = fmaxf(m, mo);
        s = s * expf(m - mn) + so * expf(mo - mn);
        m = mn;
    }
    float inv = (s > 0.f) ? 1.f / s : 0.f;

    // ---- phase 2: accumulate alpha * h[src] ----
    const int hc = (lane * CPL) / D;            // head of this lane's output cols
    const float m_c   = __shfl(m, hc);          // lane hc holds head hc's stats
    const float inv_c = __shfl(inv, hc);
    const float erc   = er[n * H + hc];
    float acc[CPL];
#pragma unroll
    for (int i = 0; i < CPL; ++i) acc[i] = 0.f;

    for (int base = 0; base < deg; base += 64) {
        int cnt = min(64, deg - base);
        int spre = (base + lane < deg) ? sorted_src[start + base + lane] : 0;
        for (int ee = 0; ee < cnt; ++ee) {
            int sr = __shfl(spre, ee);
            float v = el[sr * H + hc] + erc;
            v = (v >= 0.f) ? v : 0.2f * v;
            float w = expf(v - m_c) * inv_c;
            if (CPL == 2) {
                float2 hv = *reinterpret_cast<const float2*>(h + (long long)sr * F + lane * 2);
                acc[0] += w * hv.x;
                acc[1] += w * hv.y;
            } else {
                acc[0] += w * h[(long long)sr * F + lane];
            }
        }
    }

#pragma unroll
    for (int i = 0; i < CPL; ++i) {
        int c = lane * CPL + i;
        float o = acc[i] + bias[c];
        if (do_relu) o = fmaxf(o, 0.f);
        out[(long long)n * F + c] = o;
    }
}

// ============================================================================
// host-side layer driver
// ============================================================================
static void run_layer(const float* x, int Fin, const float* W, const float* al,
                      const float* ar, const float* bias, int H, int D,
                      const int* row_ptr, const int* sorted_src,
                      float* h, float* el, float* er, float* xnext, int do_relu,
                      hipStream_t stream) {
    const int Fout = H * D;
    const int gblocks = (N_NODES + 127) / 128;
    if (Fout == 128)
        gemm_tile<128><<<gblocks, 256, 0, stream>>>(x, W, h, Fin);
    else
        gemm_tile<64><<<gblocks, 256, 0, stream>>>(x, W, h, Fin);
    eler_kernel<<<N_NODES, Fout, 0, stream>>>(h, al, ar, el, er, H, D);
    const int ablocks = (N_NODES + 3) / 4;
    if (H == 4)
        gat_aggregate_wave<4, 32><<<ablocks, 256, 0, stream>>>(row_ptr, sorted_src, el, er, h,
                                                               bias, xnext, do_relu);
    else
        gat_aggregate_wave<1, 64><<<ablocks, 256, 0, stream>>>(row_ptr, sorted_src, el, er, h,
                                                               bias, xnext, do_relu);
}

extern "C" void kernel_launch(void* const* d_in, const int* in_sizes, int n_in,
                              void* d_out, int out_size, void* d_ws, size_t ws_size,
                              hipStream_t stream) {
    const float* feat = (const float*)d_in[0];
    const int*   src  = (const int*)d_in[1];
    const int*   dst  = (const int*)d_in[2];
    const float* W1  = (const float*)d_in[3];
    const float* al1 = (const float*)d_in[4];
    const float* ar1 = (const float*)d_in[5];
    const float* b1  = (const float*)d_in[6];
    const float* W2  = (const float*)d_in[7];
    const float* al2 = (const float*)d_in[8];
    const float* ar2 = (const float*)d_in[9];
    const float* b2  = (const float*)d_in[10];
    const float* W3  = (const float*)d_in[11];
    const float* al3 = (const float*)d_in[12];
    const float* ar3 = (const float*)d_in[13];
    const float* b3  = (const float*)d_in[14];

    // workspace carve-up
    float* ws = (float*)d_ws;
    float* h    = ws;                                   // N*128
    float* xbuf = h    + (long long)N_NODES * 128;      // N*128
    float* el   = xbuf + (long long)N_NODES * 128;      // N*4
    float* er   = el   + (long long)N_NODES * 4;        // N*4
    int* counts     = (int*)(er + (long long)N_NODES * 4);  // N
    int* row_ptr    = counts  + N_NODES;                    // N+1
    int* cursor     = row_ptr + N_NODES + 1;                // N
    int* sorted_src = cursor  + N_NODES;                    // E

    // ---- build CSR once (graph shared by all 3 layers) ----
    zero_counts<<<(N_NODES + 255) / 256, 256, 0, stream>>>(counts);
    hist_kernel<<<(N_EDGES + 255) / 256, 256, 0, stream>>>(dst, counts);
    scan_kernel<<<1, 1024, 0, stream>>>(counts, row_ptr, cursor);
    scatter_kernel<<<(N_EDGES + 255) / 256, 256, 0, stream>>>(src, dst, cursor, sorted_src);

    // layer 1: 256 -> 4x32, relu
    run_layer(feat, 256, W1, al1, ar1, b1, 4, 32, row_ptr, sorted_src,
              h, el, er, xbuf, 1, stream);
    // layer 2: 128 -> 4x32, relu
    run_layer(xbuf, 128, W2, al2, ar2, b2, 4, 32, row_ptr, sorted_src,
              h, el, er, xbuf, 1, stream);
    // layer 3: 128 -> 1x64, no relu, straight to d_out
    run_layer(xbuf, 128, W3, al3, ar3, b3, 1, 64, row_ptr, sorted_src,
              h, el, er, (float*)d_out, 0, stream);
}

// Round 4
// 446.650 us; speedup vs baseline: 8.8328x; 1.3283x over previous
//
#include <hip/hip_runtime.h>
#include <cfloat>

#define N_NODES 50000
#define N_EDGES 800000

// ============================================================================
// Register-tiled GEMM: h[N,BN] = x[N,Fin] @ W[Fin,BN]   (BN = Fout = 128 or 64)
// BM=128 rows/block, BK=32, 256 threads, 8 rows x (8|4) cols per thread.
// ============================================================================
template <int BN>
__global__ __launch_bounds__(256)
void gemm_tile(const float* __restrict__ x, const float* __restrict__ W,
               float* __restrict__ h, int Fin) {
    constexpr int BM = 128, BK = 32;
    constexpr int CN = (BN == 128) ? 8 : 4;       // cols per thread
    constexpr int NF = BN * BK / 256;             // W floats per thread (16|8)
    constexpr int NV = NF / 4;                    // float4s per thread (4|2)
    __shared__ float xs[BK][BM];
    __shared__ float ws[BK][BN];

    const int t  = threadIdx.x;
    const int r0 = blockIdx.x * BM;
    const int tr = t / 16, tc = t % 16;

    const int xrow  = t >> 1;
    const int xkoff = (t & 1) * 16;
    const bool xok  = (r0 + xrow) < N_NODES;
    const float* xrp = x + (long long)(r0 + xrow) * Fin;
    const int wk  = t >> 3;
    const int wcb = (t & 7) * NF;

    float acc[8][CN];
#pragma unroll
    for (int i = 0; i < 8; ++i)
#pragma unroll
        for (int j = 0; j < CN; ++j) acc[i][j] = 0.f;

    for (int k0 = 0; k0 < Fin; k0 += BK) {
#pragma unroll
        for (int j = 0; j < 4; ++j) {
            float4 v = make_float4(0.f, 0.f, 0.f, 0.f);
            if (xok) v = *reinterpret_cast<const float4*>(xrp + k0 + xkoff + 4 * j);
            xs[xkoff + 4 * j + 0][xrow] = v.x;
            xs[xkoff + 4 * j + 1][xrow] = v.y;
            xs[xkoff + 4 * j + 2][xrow] = v.z;
            xs[xkoff + 4 * j + 3][xrow] = v.w;
        }
#pragma unroll
        for (int j = 0; j < NV; ++j) {
            float4 v = *reinterpret_cast<const float4*>(W + (long long)(k0 + wk) * BN + wcb + 4 * j);
            *reinterpret_cast<float4*>(&ws[wk][wcb + 4 * j]) = v;
        }
        __syncthreads();

#pragma unroll
        for (int kk = 0; kk < BK; ++kk) {
            float ra[8], rb[CN];
            float4 a0 = *reinterpret_cast<const float4*>(&xs[kk][tr * 4]);
            float4 a1 = *reinterpret_cast<const float4*>(&xs[kk][tr * 4 + 64]);
            ra[0] = a0.x; ra[1] = a0.y; ra[2] = a0.z; ra[3] = a0.w;
            ra[4] = a1.x; ra[5] = a1.y; ra[6] = a1.z; ra[7] = a1.w;
            float4 b0 = *reinterpret_cast<const float4*>(&ws[kk][tc * 4]);
            rb[0] = b0.x; rb[1] = b0.y; rb[2] = b0.z; rb[3] = b0.w;
            if (BN == 128) {
                float4 b1 = *reinterpret_cast<const float4*>(&ws[kk][tc * 4 + 64]);
                rb[4] = b1.x; rb[5] = b1.y; rb[6] = b1.z; rb[7] = b1.w;
            }
#pragma unroll
            for (int i = 0; i < 8; ++i)
#pragma unroll
                for (int j = 0; j < CN; ++j) acc[i][j] += ra[i] * rb[j];
        }
        __syncthreads();
    }

#pragma unroll
    for (int i = 0; i < 8; ++i) {
        int row = r0 + tr * 4 + (i / 4) * 64 + (i % 4);
        if (row < N_NODES) {
            float4 v0 = make_float4(acc[i][0], acc[i][1], acc[i][2], acc[i][3]);
            *reinterpret_cast<float4*>(h + (long long)row * BN + tc * 4) = v0;
            if (BN == 128) {
                float4 v1 = make_float4(acc[i][4], acc[i][5], acc[i][6], acc[i][7]);
                *reinterpret_cast<float4*>(h + (long long)row * BN + tc * 4 + 64) = v1;
            }
        }
    }
}

// ============================================================================
// Wave-per-node attention logits via shfl reduction. 4 nodes per 256-block.
// ============================================================================
template <int H, int D>
__global__ __launch_bounds__(256)
void eler_wave(const float* __restrict__ h, const float* __restrict__ al,
               const float* __restrict__ ar, float* __restrict__ el,
               float* __restrict__ er) {
    constexpr int F   = H * D;
    constexpr int CPL = F / 64;       // 2 (F=128) or 1 (F=64)
    constexpr int LPH = 64 / H;       // lanes per head
    const int lane = threadIdx.x & 63;
    const int wid  = threadIdx.x >> 6;
    const int n    = blockIdx.x * 4 + wid;
    if (n >= N_NODES) return;

    float a, b;
    if (CPL == 2) {
        float2 v = *reinterpret_cast<const float2*>(h + (long long)n * F + lane * 2);
        float2 A = *reinterpret_cast<const float2*>(al + lane * 2);
        float2 B = *reinterpret_cast<const float2*>(ar + lane * 2);
        a = v.x * A.x + v.y * A.y;
        b = v.x * B.x + v.y * B.y;
    } else {
        float v = h[(long long)n * F + lane];
        a = v * al[lane];
        b = v * ar[lane];
    }
#pragma unroll
    for (int off = 1; off < LPH; off <<= 1) {
        a += __shfl_xor(a, off);
        b += __shfl_xor(b, off);
    }
    if ((lane & (LPH - 1)) == 0) {
        int hh = lane / LPH;
        el[n * H + hh] = a;
        er[n * H + hh] = b;
    }
}

// ============================================================================
// CSR build (once per call; graph shared by all 3 layers)
// ============================================================================
__global__ void zero_counts(int* __restrict__ counts) {
    int i = blockIdx.x * blockDim.x + threadIdx.x;
    if (i < N_NODES) counts[i] = 0;
}

__global__ void hist_kernel(const int* __restrict__ dst, int* __restrict__ counts) {
    int e = blockIdx.x * blockDim.x + threadIdx.x;
    if (e < N_EDGES) atomicAdd(counts + dst[e], 1);
}

// phase 1: per-1024-block local exclusive scan (wave shfl + LDS wave sums)
__global__ __launch_bounds__(1024)
void scan_local(const int* __restrict__ counts, int* __restrict__ row_ptr,
                int* __restrict__ bsum) {
    __shared__ int wsums[16];
    const int tid = threadIdx.x, lane = tid & 63, wid = tid >> 6;
    const int i = blockIdx.x * 1024 + tid;
    int v = (i < N_NODES) ? counts[i] : 0;
    int incl = v;
#pragma unroll
    for (int off = 1; off < 64; off <<= 1) {
        int t = __shfl_up(incl, off);
        if (lane >= off) incl += t;
    }
    if (lane == 63) wsums[wid] = incl;
    __syncthreads();
    if (wid == 0) {
        int ws = (lane < 16) ? wsums[lane] : 0;
#pragma unroll
        for (int off = 1; off < 16; off <<= 1) {
            int t = __shfl_up(ws, off);
            if (lane >= off) ws += t;
        }
        if (lane < 16) wsums[lane] = ws;             // inclusive wave sums
        if (lane == 15) bsum[blockIdx.x] = ws;       // block total
    }
    __syncthreads();
    int woff = (wid > 0) ? wsums[wid - 1] : 0;
    if (i < N_NODES) row_ptr[i] = woff + incl - v;   // local exclusive
}

// phase 2: single-wave exclusive scan of <=64 block sums; writes row_ptr[N]
__global__ void scan_bsums(int* __restrict__ bsum, int* __restrict__ row_ptr, int nb) {
    const int lane = threadIdx.x;
    int v = (lane < nb) ? bsum[lane] : 0;
    int incl = v;
#pragma unroll
    for (int off = 1; off < 64; off <<= 1) {
        int t = __shfl_up(incl, off);
        if (lane >= off) incl += t;
    }
    if (lane < nb) bsum[lane] = incl - v;            // exclusive
    if (lane == 63) row_ptr[N_NODES] = incl;         // grand total
}

// phase 3: add block offsets, copy to cursor
__global__ void scan_add(int* __restrict__ row_ptr, const int* __restrict__ bsum,
                         int* __restrict__ cursor) {
    int i = blockIdx.x * blockDim.x + threadIdx.x;
    if (i < N_NODES) {
        int r = row_ptr[i] + bsum[i >> 10];
        row_ptr[i] = r;
        cursor[i]  = r;
    }
}

__global__ void scatter_kernel(const int* __restrict__ src, const int* __restrict__ dst,
                               int* __restrict__ cursor, int* __restrict__ sorted_src) {
    int e = blockIdx.x * blockDim.x + threadIdx.x;
    if (e >= N_EDGES) return;
    int pos = atomicAdd(cursor + dst[e], 1);
    sorted_src[pos] = src[e];
}

// ============================================================================
// Wave-per-node fused softmax + aggregate + bias (+relu). 4 waves/block,
// shfl-only reductions, unrolled full-chunk inner loop for MLP.
// ============================================================================
template <int H, int D>
__global__ __launch_bounds__(256)
void gat_aggregate_wave(const int* __restrict__ row_ptr, const int* __restrict__ sorted_src,
                        const float* __restrict__ el, const float* __restrict__ er,
                        const float* __restrict__ h, const float* __restrict__ bias,
                        float* __restrict__ out, int do_relu) {
    constexpr int F   = H * D;
    constexpr int CPL = F / 64;   // cols per lane: 2 (F=128) or 1 (F=64)
    const int lane = threadIdx.x & 63;
    const int wid  = threadIdx.x >> 6;
    const int n    = blockIdx.x * 4 + wid;
    if (n >= N_NODES) return;

    const int start = row_ptr[n];
    const int deg   = row_ptr[n + 1] - start;

    // ---- phase 1: online softmax stats; lane handles head lane%H ----
    const int h1 = lane % H;
    const float er1 = er[n * H + h1];
    float m = -FLT_MAX, s = 0.f;
    for (int ei = lane / H; ei < deg; ei += 64 / H) {
        int sr = sorted_src[start + ei];
        float v = el[sr * H + h1] + er1;
        v = (v >= 0.f) ? v : 0.2f * v;
        if (v > m) { s = s * expf(m - v) + 1.f; m = v; }
        else       { s += expf(v - m); }
    }
#pragma unroll
    for (int off = H; off < 64; off <<= 1) {
        float mo = __shfl_xor(m, off);
        float so = __shfl_xor(s, off);
        float mn = fmaxf(m, mo);
        s = s * expf(m - mn) + so * expf(mo - mn);
        m = mn;
    }
    float inv = (s > 0.f) ? 1.f / s : 0.f;

    // ---- phase 2: accumulate alpha * h[src] ----
    const int hc = (lane * CPL) / D;
    const float m_c   = __shfl(m, hc);
    const float inv_c = __shfl(inv, hc);
    const float erc   = er[n * H + hc];
    float acc[CPL];
#pragma unroll
    for (int i = 0; i < CPL; ++i) acc[i] = 0.f;

#define AGG_BODY(EE)                                                                 \
    {                                                                                \
        int sr = __shfl(spre, (EE));                                                 \
        float v = el[sr * H + hc] + erc;                                             \
        v = (v >= 0.f) ? v : 0.2f * v;                                               \
        float w = expf(v - m_c) * inv_c;                                             \
        if (CPL == 2) {                                                              \
            float2 hv = *reinterpret_cast<const float2*>(h + (long long)sr * F + lane * 2); \
            acc[0] += w * hv.x;                                                      \
            acc[1] += w * hv.y;                                                      \
        } else {                                                                     \
            acc[0] += w * h[(long long)sr * F + lane];                               \
        }                                                                            \
    }

    int base = 0;
    for (; base + 64 <= deg; base += 64) {
        int spre = sorted_src[start + base + lane];
#pragma unroll 4
        for (int ee = 0; ee < 64; ++ee) AGG_BODY(ee)
    }
    if (base < deg) {
        int rem = deg - base;
        int spre = (lane < rem) ? sorted_src[start + base + lane] : 0;
        for (int ee = 0; ee < rem; ++ee) AGG_BODY(ee)
    }
#undef AGG_BODY

#pragma unroll
    for (int i = 0; i < CPL; ++i) {
        int c = lane * CPL + i;
        float o = acc[i] + bias[c];
        if (do_relu) o = fmaxf(o, 0.f);
        out[(long long)n * F + c] = o;
    }
}

// ============================================================================
// host-side layer driver
// ============================================================================
static void run_layer(const float* x, int Fin, const float* W, const float* al,
                      const float* ar, const float* bias, int H, int D,
                      const int* row_ptr, const int* sorted_src,
                      float* h, float* el, float* er, float* xnext, int do_relu,
                      hipStream_t stream) {
    const int gblocks = (N_NODES + 127) / 128;
    const int nblocks = (N_NODES + 3) / 4;
    if (H == 4) {
        gemm_tile<128><<<gblocks, 256, 0, stream>>>(x, W, h, Fin);
        eler_wave<4, 32><<<nblocks, 256, 0, stream>>>(h, al, ar, el, er);
        gat_aggregate_wave<4, 32><<<nblocks, 256, 0, stream>>>(row_ptr, sorted_src, el, er, h,
                                                               bias, xnext, do_relu);
    } else {
        gemm_tile<64><<<gblocks, 256, 0, stream>>>(x, W, h, Fin);
        eler_wave<1, 64><<<nblocks, 256, 0, stream>>>(h, al, ar, el, er);
        gat_aggregate_wave<1, 64><<<nblocks, 256, 0, stream>>>(row_ptr, sorted_src, el, er, h,
                                                               bias, xnext, do_relu);
    }
}

extern "C" void kernel_launch(void* const* d_in, const int* in_sizes, int n_in,
                              void* d_out, int out_size, void* d_ws, size_t ws_size,
                              hipStream_t stream) {
    const float* feat = (const float*)d_in[0];
    const int*   src  = (const int*)d_in[1];
    const int*   dst  = (const int*)d_in[2];
    const float* W1  = (const float*)d_in[3];
    const float* al1 = (const float*)d_in[4];
    const float* ar1 = (const float*)d_in[5];
    const float* b1  = (const float*)d_in[6];
    const float* W2  = (const float*)d_in[7];
    const float* al2 = (const float*)d_in[8];
    const float* ar2 = (const float*)d_in[9];
    const float* b2  = (const float*)d_in[10];
    const float* W3  = (const float*)d_in[11];
    const float* al3 = (const float*)d_in[12];
    const float* ar3 = (const float*)d_in[13];
    const float* b3  = (const float*)d_in[14];

    // workspace carve-up
    float* ws = (float*)d_ws;
    float* h    = ws;                                   // N*128
    float* xbuf = h    + (long long)N_NODES * 128;      // N*128
    float* el   = xbuf + (long long)N_NODES * 128;      // N*4
    float* er   = el   + (long long)N_NODES * 4;        // N*4
    int* counts     = (int*)(er + (long long)N_NODES * 4);  // N
    int* row_ptr    = counts  + N_NODES;                    // N+1
    int* cursor     = row_ptr + N_NODES + 1;                // N
    int* sorted_src = cursor  + N_NODES;                    // E
    int* bsum       = sorted_src + N_EDGES;                 // 64

    // ---- build CSR once (graph shared by all 3 layers) ----
    const int SB = (N_NODES + 1023) / 1024;   // 49
    zero_counts<<<(N_NODES + 255) / 256, 256, 0, stream>>>(counts);
    hist_kernel<<<(N_EDGES + 255) / 256, 256, 0, stream>>>(dst, counts);
    scan_local<<<SB, 1024, 0, stream>>>(counts, row_ptr, bsum);
    scan_bsums<<<1, 64, 0, stream>>>(bsum, row_ptr, SB);
    scan_add<<<(N_NODES + 255) / 256, 256, 0, stream>>>(row_ptr, bsum, cursor);
    scatter_kernel<<<(N_EDGES + 255) / 256, 256, 0, stream>>>(src, dst, cursor, sorted_src);

    // layer 1: 256 -> 4x32, relu
    run_layer(feat, 256, W1, al1, ar1, b1, 4, 32, row_ptr, sorted_src,
              h, el, er, xbuf, 1, stream);
    // layer 2: 128 -> 4x32, relu
    run_layer(xbuf, 128, W2, al2, ar2, b2, 4, 32, row_ptr, sorted_src,
              h, el, er, xbuf, 1, stream);
    // layer 3: 128 -> 1x64, no relu, straight to d_out
    run_layer(xbuf, 128, W3, al3, ar3, b3, 1, 64, row_ptr, sorted_src,
              h, el, er, (float*)d_out, 0, stream);
}

// Round 6
// 445.431 us; speedup vs baseline: 8.8570x; 1.0027x over previous
//
#include <hip/hip_runtime.h>
#include <cfloat>

#define N_NODES 50000
#define N_EDGES 800000

// ============================================================================
// Register-tiled GEMM: h[N,BN] = x[N,Fin] @ W[Fin,BN]   (BN = Fout = 128 or 64)
// ============================================================================
template <int BN>
__global__ __launch_bounds__(256)
void gemm_tile(const float* __restrict__ x, const float* __restrict__ W,
               float* __restrict__ h, int Fin) {
    constexpr int BM = 128, BK = 32;
    constexpr int CN = (BN == 128) ? 8 : 4;
    constexpr int NF = BN * BK / 256;
    constexpr int NV = NF / 4;
    __shared__ float xs[BK][BM];
    __shared__ float ws[BK][BN];

    const int t  = threadIdx.x;
    const int r0 = blockIdx.x * BM;
    const int tr = t / 16, tc = t % 16;

    const int xrow  = t >> 1;
    const int xkoff = (t & 1) * 16;
    const bool xok  = (r0 + xrow) < N_NODES;
    const float* xrp = x + (long long)(r0 + xrow) * Fin;
    const int wk  = t >> 3;
    const int wcb = (t & 7) * NF;

    float acc[8][CN];
#pragma unroll
    for (int i = 0; i < 8; ++i)
#pragma unroll
        for (int j = 0; j < CN; ++j) acc[i][j] = 0.f;

    for (int k0 = 0; k0 < Fin; k0 += BK) {
#pragma unroll
        for (int j = 0; j < 4; ++j) {
            float4 v = make_float4(0.f, 0.f, 0.f, 0.f);
            if (xok) v = *reinterpret_cast<const float4*>(xrp + k0 + xkoff + 4 * j);
            xs[xkoff + 4 * j + 0][xrow] = v.x;
            xs[xkoff + 4 * j + 1][xrow] = v.y;
            xs[xkoff + 4 * j + 2][xrow] = v.z;
            xs[xkoff + 4 * j + 3][xrow] = v.w;
        }
#pragma unroll
        for (int j = 0; j < NV; ++j) {
            float4 v = *reinterpret_cast<const float4*>(W + (long long)(k0 + wk) * BN + wcb + 4 * j);
            *reinterpret_cast<float4*>(&ws[wk][wcb + 4 * j]) = v;
        }
        __syncthreads();

#pragma unroll
        for (int kk = 0; kk < BK; ++kk) {
            float ra[8], rb[CN];
            float4 a0 = *reinterpret_cast<const float4*>(&xs[kk][tr * 4]);
            float4 a1 = *reinterpret_cast<const float4*>(&xs[kk][tr * 4 + 64]);
            ra[0] = a0.x; ra[1] = a0.y; ra[2] = a0.z; ra[3] = a0.w;
            ra[4] = a1.x; ra[5] = a1.y; ra[6] = a1.z; ra[7] = a1.w;
            float4 b0 = *reinterpret_cast<const float4*>(&ws[kk][tc * 4]);
            rb[0] = b0.x; rb[1] = b0.y; rb[2] = b0.z; rb[3] = b0.w;
            if (BN == 128) {
                float4 b1 = *reinterpret_cast<const float4*>(&ws[kk][tc * 4 + 64]);
                rb[4] = b1.x; rb[5] = b1.y; rb[6] = b1.z; rb[7] = b1.w;
            }
#pragma unroll
            for (int i = 0; i < 8; ++i)
#pragma unroll
                for (int j = 0; j < CN; ++j) acc[i][j] += ra[i] * rb[j];
        }
        __syncthreads();
    }

#pragma unroll
    for (int i = 0; i < 8; ++i) {
        int row = r0 + tr * 4 + (i / 4) * 64 + (i % 4);
        if (row < N_NODES) {
            float4 v0 = make_float4(acc[i][0], acc[i][1], acc[i][2], acc[i][3]);
            *reinterpret_cast<float4*>(h + (long long)row * BN + tc * 4) = v0;
            if (BN == 128) {
                float4 v1 = make_float4(acc[i][4], acc[i][5], acc[i][6], acc[i][7]);
                *reinterpret_cast<float4*>(h + (long long)row * BN + tc * 4 + 64) = v1;
            }
        }
    }
}

// ============================================================================
// Wave-per-node attention logits via shfl reduction. 4 nodes per 256-block.
// ============================================================================
template <int H, int D>
__global__ __launch_bounds__(256)
void eler_wave(const float* __restrict__ h, const float* __restrict__ al,
               const float* __restrict__ ar, float* __restrict__ el,
               float* __restrict__ er) {
    constexpr int F   = H * D;
    constexpr int CPL = F / 64;
    constexpr int LPH = 64 / H;
    const int lane = threadIdx.x & 63;
    const int wid  = threadIdx.x >> 6;
    const int n    = blockIdx.x * 4 + wid;
    if (n >= N_NODES) return;

    float a, b;
    if (CPL == 2) {
        float2 v = *reinterpret_cast<const float2*>(h + (long long)n * F + lane * 2);
        float2 A = *reinterpret_cast<const float2*>(al + lane * 2);
        float2 B = *reinterpret_cast<const float2*>(ar + lane * 2);
        a = v.x * A.x + v.y * A.y;
        b = v.x * B.x + v.y * B.y;
    } else {
        float v = h[(long long)n * F + lane];
        a = v * al[lane];
        b = v * ar[lane];
    }
#pragma unroll
    for (int off = 1; off < LPH; off <<= 1) {
        a += __shfl_xor(a, off);
        b += __shfl_xor(b, off);
    }
    if ((lane & (LPH - 1)) == 0) {
        int hh = lane / LPH;
        el[n * H + hh] = a;
        er[n * H + hh] = b;
    }
}

// ============================================================================
// CSR build (once per call; graph shared by all 3 layers)
// ============================================================================
__global__ void zero_counts(int* __restrict__ counts) {
    int i = blockIdx.x * blockDim.x + threadIdx.x;
    if (i < N_NODES) counts[i] = 0;
}

__global__ void hist_kernel(const int* __restrict__ dst, int* __restrict__ counts) {
    int e = blockIdx.x * blockDim.x + threadIdx.x;
    if (e < N_EDGES) atomicAdd(counts + dst[e], 1);
}

__global__ __launch_bounds__(1024)
void scan_local(const int* __restrict__ counts, int* __restrict__ row_ptr,
                int* __restrict__ bsum) {
    __shared__ int wsums[16];
    const int tid = threadIdx.x, lane = tid & 63, wid = tid >> 6;
    const int i = blockIdx.x * 1024 + tid;
    int v = (i < N_NODES) ? counts[i] : 0;
    int incl = v;
#pragma unroll
    for (int off = 1; off < 64; off <<= 1) {
        int t = __shfl_up(incl, off);
        if (lane >= off) incl += t;
    }
    if (lane == 63) wsums[wid] = incl;
    __syncthreads();
    if (wid == 0) {
        int ws = (lane < 16) ? wsums[lane] : 0;
#pragma unroll
        for (int off = 1; off < 16; off <<= 1) {
            int t = __shfl_up(ws, off);
            if (lane >= off) ws += t;
        }
        if (lane < 16) wsums[lane] = ws;
        if (lane == 15) bsum[blockIdx.x] = ws;
    }
    __syncthreads();
    int woff = (wid > 0) ? wsums[wid - 1] : 0;
    if (i < N_NODES) row_ptr[i] = woff + incl - v;
}

__global__ void scan_bsums(int* __restrict__ bsum, int* __restrict__ row_ptr, int nb) {
    const int lane = threadIdx.x;
    int v = (lane < nb) ? bsum[lane] : 0;
    int incl = v;
#pragma unroll
    for (int off = 1; off < 64; off <<= 1) {
        int t = __shfl_up(incl, off);
        if (lane >= off) incl += t;
    }
    if (lane < nb) bsum[lane] = incl - v;
    if (lane == 63) row_ptr[N_NODES] = incl;
}

__global__ void scan_add(int* __restrict__ row_ptr, const int* __restrict__ bsum,
                         int* __restrict__ cursor) {
    int i = blockIdx.x * blockDim.x + threadIdx.x;
    if (i < N_NODES) {
        int r = row_ptr[i] + bsum[i >> 10];
        row_ptr[i] = r;
        cursor[i]  = r;
    }
}

__global__ void scatter_kernel(const int* __restrict__ src, const int* __restrict__ dst,
                               int* __restrict__ cursor, int* __restrict__ sorted_src) {
    int e = blockIdx.x * blockDim.x + threadIdx.x;
    if (e >= N_EDGES) return;
    int pos = atomicAdd(cursor + dst[e], 1);
    sorted_src[pos] = src[e];
}

// ============================================================================
// Wave-per-node aggregate, 4 heads (F=128), dedup'd weights — FIXED ownership:
// lane l (head hh=l>>4) computes weights for the 4 edges ee ≡ l (mod 16) of its
// OWN head. Reader (head hc) pulls weight(ee,hc) from lane (ee&15)|(hc<<4),
// register ee>>4 (compile-time). 4 exps per edge total; denom applied at end.
// ============================================================================
__global__ __launch_bounds__(256)
void gat_agg_h4(const int* __restrict__ row_ptr, const int* __restrict__ sorted_src,
                const float* __restrict__ el, const float* __restrict__ er,
                const float* __restrict__ h, const float* __restrict__ bias,
                float* __restrict__ out, int do_relu) {
    const int lane = threadIdx.x & 63;
    const int wid  = threadIdx.x >> 6;
    const int n    = blockIdx.x * 4 + wid;
    if (n >= N_NODES) return;

    const int start = row_ptr[n];
    const int deg   = row_ptr[n + 1] - start;

    const float4 ern = *reinterpret_cast<const float4*>(er + n * 4);

    // ---- phase 1: per-head max (no exp) ----
    float m0 = -FLT_MAX, m1 = -FLT_MAX, m2 = -FLT_MAX, m3 = -FLT_MAX;
    for (int base = 0; base < deg; base += 64) {
        int idx = base + lane;
        if (idx < deg) {
            int sr = sorted_src[start + idx];
            float4 e4 = *reinterpret_cast<const float4*>(el + sr * 4);
            float v0 = e4.x + ern.x; v0 = (v0 >= 0.f) ? v0 : 0.2f * v0;
            float v1 = e4.y + ern.y; v1 = (v1 >= 0.f) ? v1 : 0.2f * v1;
            float v2 = e4.z + ern.z; v2 = (v2 >= 0.f) ? v2 : 0.2f * v2;
            float v3 = e4.w + ern.w; v3 = (v3 >= 0.f) ? v3 : 0.2f * v3;
            m0 = fmaxf(m0, v0); m1 = fmaxf(m1, v1);
            m2 = fmaxf(m2, v2); m3 = fmaxf(m3, v3);
        }
    }
#pragma unroll
    for (int off = 1; off < 64; off <<= 1) {
        m0 = fmaxf(m0, __shfl_xor(m0, off));
        m1 = fmaxf(m1, __shfl_xor(m1, off));
        m2 = fmaxf(m2, __shfl_xor(m2, off));
        m3 = fmaxf(m3, __shfl_xor(m3, off));
    }

    // per-lane head (same for weight-owner and reader roles)
    const int hc = lane >> 4;
    const int hsh = hc << 4;
    const float ma  = (hc & 2) ? m2 : m0;
    const float mb  = (hc & 2) ? m3 : m1;
    const float m_c = (hc & 1) ? mb : ma;
    const float ea  = (hc & 2) ? ern.z : ern.x;
    const float eb  = (hc & 2) ? ern.w : ern.y;
    const float erc = (hc & 1) ? eb : ea;

    float acc0 = 0.f, acc1 = 0.f, ssum = 0.f;

#define AGG2(EE)                                                                      \
    {                                                                                 \
        int   se = __shfl(sr, (EE));                                                  \
        float we = __shfl(w[(EE) >> 4], ((EE) & 15) | hsh);                           \
        float2 hv = *reinterpret_cast<const float2*>(h + (long long)se * 128 + lane * 2); \
        acc0 += we * hv.x; acc1 += we * hv.y; ssum += we;                             \
    }

    for (int base = 0; base < deg; base += 64) {
        int cnt = min(64, deg - base);
        int sr = 0;
        if (lane < cnt) sr = sorted_src[start + base + lane];

        // weights for my head's 4 edges: ee = (lane&15) + 16k
        float w[4];
#pragma unroll
        for (int k = 0; k < 4; ++k) {
            int ee = (lane & 15) + 16 * k;
            int sk = __shfl(sr, ee);
            float v = el[sk * 4 + hc] + erc;
            v = (v >= 0.f) ? v : 0.2f * v;
            w[k] = (ee < cnt) ? __expf(v - m_c) : 0.f;
        }

        if (cnt == 64) {
#pragma unroll 8
            for (int ee = 0; ee < 64; ++ee) AGG2(ee)
        } else {
#pragma unroll
            for (int k = 0; k < 4; ++k) {
                int lim = min(16, cnt - 16 * k);
                for (int e2 = 0; e2 < lim; ++e2) {
                    int   se = __shfl(sr, 16 * k + e2);
                    float we = __shfl(w[k], e2 | hsh);
                    float2 hv = *reinterpret_cast<const float2*>(h + (long long)se * 128 + lane * 2);
                    acc0 += we * hv.x; acc1 += we * hv.y; ssum += we;
                }
            }
        }
    }
#undef AGG2

    float inv = (ssum > 0.f) ? 1.f / ssum : 0.f;
    int c = lane * 2;
    float o0 = acc0 * inv + bias[c];
    float o1 = acc1 * inv + bias[c + 1];
    if (do_relu) { o0 = fmaxf(o0, 0.f); o1 = fmaxf(o1, 0.f); }
    *reinterpret_cast<float2*>(out + (long long)n * 128 + c) = make_float2(o0, o1);
}

// ---- single-head (F=64) variant: owner lane == edge lane, no head selection ----
__global__ __launch_bounds__(256)
void gat_agg_h1(const int* __restrict__ row_ptr, const int* __restrict__ sorted_src,
                const float* __restrict__ el, const float* __restrict__ er,
                const float* __restrict__ h, const float* __restrict__ bias,
                float* __restrict__ out, int do_relu) {
    const int lane = threadIdx.x & 63;
    const int wid  = threadIdx.x >> 6;
    const int n    = blockIdx.x * 4 + wid;
    if (n >= N_NODES) return;

    const int start = row_ptr[n];
    const int deg   = row_ptr[n + 1] - start;
    const float ern = er[n];

    float m = -FLT_MAX;
    for (int base = 0; base < deg; base += 64) {
        int idx = base + lane;
        if (idx < deg) {
            int sr = sorted_src[start + idx];
            float v = el[sr] + ern;
            v = (v >= 0.f) ? v : 0.2f * v;
            m = fmaxf(m, v);
        }
    }
#pragma unroll
    for (int off = 1; off < 64; off <<= 1) m = fmaxf(m, __shfl_xor(m, off));

    float acc = 0.f, ssum = 0.f;

#define AGG1(EE)                                                       \
    {                                                                  \
        int   se = __shfl(sr, (EE));                                   \
        float we = __shfl(w, (EE));                                    \
        acc += we * h[(long long)se * 64 + lane];                      \
        ssum += we;                                                    \
    }

    for (int base = 0; base < deg; base += 64) {
        int cnt = min(64, deg - base);
        int sr = 0;
        float w = 0.f;
        if (lane < cnt) {
            sr = sorted_src[start + base + lane];
            float v = el[sr] + ern;
            v = (v >= 0.f) ? v : 0.2f * v;
            w = __expf(v - m);
        }
        if (cnt == 64) {
#pragma unroll 8
            for (int ee = 0; ee < 64; ++ee) AGG1(ee)
        } else {
            for (int ee = 0; ee < cnt; ++ee) AGG1(ee)
        }
    }
#undef AGG1

    float inv = (ssum > 0.f) ? 1.f / ssum : 0.f;
    float o = acc * inv + bias[lane];
    if (do_relu) o = fmaxf(o, 0.f);
    out[(long long)n * 64 + lane] = o;
}

// ============================================================================
// host-side layer driver
// ============================================================================
static void run_layer(const float* x, int Fin, const float* W, const float* al,
                      const float* ar, const float* bias, int H, int D,
                      const int* row_ptr, const int* sorted_src,
                      float* h, float* el, float* er, float* xnext, int do_relu,
                      hipStream_t stream) {
    const int gblocks = (N_NODES + 127) / 128;
    const int nblocks = (N_NODES + 3) / 4;
    if (H == 4) {
        gemm_tile<128><<<gblocks, 256, 0, stream>>>(x, W, h, Fin);
        eler_wave<4, 32><<<nblocks, 256, 0, stream>>>(h, al, ar, el, er);
        gat_agg_h4<<<nblocks, 256, 0, stream>>>(row_ptr, sorted_src, el, er, h,
                                                bias, xnext, do_relu);
    } else {
        gemm_tile<64><<<gblocks, 256, 0, stream>>>(x, W, h, Fin);
        eler_wave<1, 64><<<nblocks, 256, 0, stream>>>(h, al, ar, el, er);
        gat_agg_h1<<<nblocks, 256, 0, stream>>>(row_ptr, sorted_src, el, er, h,
                                                bias, xnext, do_relu);
    }
}

extern "C" void kernel_launch(void* const* d_in, const int* in_sizes, int n_in,
                              void* d_out, int out_size, void* d_ws, size_t ws_size,
                              hipStream_t stream) {
    const float* feat = (const float*)d_in[0];
    const int*   src  = (const int*)d_in[1];
    const int*   dst  = (const int*)d_in[2];
    const float* W1  = (const float*)d_in[3];
    const float* al1 = (const float*)d_in[4];
    const float* ar1 = (const float*)d_in[5];
    const float* b1  = (const float*)d_in[6];
    const float* W2  = (const float*)d_in[7];
    const float* al2 = (const float*)d_in[8];
    const float* ar2 = (const float*)d_in[9];
    const float* b2  = (const float*)d_in[10];
    const float* W3  = (const float*)d_in[11];
    const float* al3 = (const float*)d_in[12];
    const float* ar3 = (const float*)d_in[13];
    const float* b3  = (const float*)d_in[14];

    // workspace carve-up
    float* ws = (float*)d_ws;
    float* h    = ws;                                   // N*128
    float* xbuf = h    + (long long)N_NODES * 128;      // N*128
    float* el   = xbuf + (long long)N_NODES * 128;      // N*4
    float* er   = el   + (long long)N_NODES * 4;        // N*4
    int* counts     = (int*)(er + (long long)N_NODES * 4);  // N
    int* row_ptr    = counts  + N_NODES;                    // N+1
    int* cursor     = row_ptr + N_NODES + 1;                // N
    int* sorted_src = cursor  + N_NODES;                    // E
    int* bsum       = sorted_src + N_EDGES;                 // 64

    // ---- build CSR once (graph shared by all 3 layers) ----
    const int SB = (N_NODES + 1023) / 1024;   // 49
    zero_counts<<<(N_NODES + 255) / 256, 256, 0, stream>>>(counts);
    hist_kernel<<<(N_EDGES + 255) / 256, 256, 0, stream>>>(dst, counts);
    scan_local<<<SB, 1024, 0, stream>>>(counts, row_ptr, bsum);
    scan_bsums<<<1, 64, 0, stream>>>(bsum, row_ptr, SB);
    scan_add<<<(N_NODES + 255) / 256, 256, 0, stream>>>(row_ptr, bsum, cursor);
    scatter_kernel<<<(N_EDGES + 255) / 256, 256, 0, stream>>>(src, dst, cursor, sorted_src);

    // layer 1: 256 -> 4x32, relu
    run_layer(feat, 256, W1, al1, ar1, b1, 4, 32, row_ptr, sorted_src,
              h, el, er, xbuf, 1, stream);
    // layer 2: 128 -> 4x32, relu
    run_layer(xbuf, 128, W2, al2, ar2, b2, 4, 32, row_ptr, sorted_src,
              h, el, er, xbuf, 1, stream);
    // layer 3: 128 -> 1x64, no relu, straight to d_out
    run_layer(xbuf, 128, W3, al3, ar3, b3, 1, 64, row_ptr, sorted_src,
              h, el, er, (float*)d_out, 0, stream);
}

// Round 7
// 430.709 us; speedup vs baseline: 9.1598x; 1.0342x over previous
//
#include <hip/hip_runtime.h>
#include <hip/hip_fp16.h>
#include <cfloat>

#define N_NODES 50000
#define N_EDGES 800000

// ============================================================================
// Register-tiled GEMM: h[N,BN] = x[N,Fin] @ W[Fin,BN], output packed fp16.
// ============================================================================
template <int BN>
__global__ __launch_bounds__(256)
void gemm_tile(const float* __restrict__ x, const float* __restrict__ W,
               __half* __restrict__ hh, int Fin) {
    constexpr int BM = 128, BK = 32;
    constexpr int CN = (BN == 128) ? 8 : 4;
    constexpr int NF = BN * BK / 256;
    constexpr int NV = NF / 4;
    __shared__ float xs[BK][BM];
    __shared__ float ws[BK][BN];

    const int t  = threadIdx.x;
    const int r0 = blockIdx.x * BM;
    const int tr = t / 16, tc = t % 16;

    const int xrow  = t >> 1;
    const int xkoff = (t & 1) * 16;
    const bool xok  = (r0 + xrow) < N_NODES;
    const float* xrp = x + (long long)(r0 + xrow) * Fin;
    const int wk  = t >> 3;
    const int wcb = (t & 7) * NF;

    float acc[8][CN];
#pragma unroll
    for (int i = 0; i < 8; ++i)
#pragma unroll
        for (int j = 0; j < CN; ++j) acc[i][j] = 0.f;

    for (int k0 = 0; k0 < Fin; k0 += BK) {
#pragma unroll
        for (int j = 0; j < 4; ++j) {
            float4 v = make_float4(0.f, 0.f, 0.f, 0.f);
            if (xok) v = *reinterpret_cast<const float4*>(xrp + k0 + xkoff + 4 * j);
            xs[xkoff + 4 * j + 0][xrow] = v.x;
            xs[xkoff + 4 * j + 1][xrow] = v.y;
            xs[xkoff + 4 * j + 2][xrow] = v.z;
            xs[xkoff + 4 * j + 3][xrow] = v.w;
        }
#pragma unroll
        for (int j = 0; j < NV; ++j) {
            float4 v = *reinterpret_cast<const float4*>(W + (long long)(k0 + wk) * BN + wcb + 4 * j);
            *reinterpret_cast<float4*>(&ws[wk][wcb + 4 * j]) = v;
        }
        __syncthreads();

#pragma unroll
        for (int kk = 0; kk < BK; ++kk) {
            float ra[8], rb[CN];
            float4 a0 = *reinterpret_cast<const float4*>(&xs[kk][tr * 4]);
            float4 a1 = *reinterpret_cast<const float4*>(&xs[kk][tr * 4 + 64]);
            ra[0] = a0.x; ra[1] = a0.y; ra[2] = a0.z; ra[3] = a0.w;
            ra[4] = a1.x; ra[5] = a1.y; ra[6] = a1.z; ra[7] = a1.w;
            float4 b0 = *reinterpret_cast<const float4*>(&ws[kk][tc * 4]);
            rb[0] = b0.x; rb[1] = b0.y; rb[2] = b0.z; rb[3] = b0.w;
            if (BN == 128) {
                float4 b1 = *reinterpret_cast<const float4*>(&ws[kk][tc * 4 + 64]);
                rb[4] = b1.x; rb[5] = b1.y; rb[6] = b1.z; rb[7] = b1.w;
            }
#pragma unroll
            for (int i = 0; i < 8; ++i)
#pragma unroll
                for (int j = 0; j < CN; ++j) acc[i][j] += ra[i] * rb[j];
        }
        __syncthreads();
    }

#pragma unroll
    for (int i = 0; i < 8; ++i) {
        int row = r0 + tr * 4 + (i / 4) * 64 + (i % 4);
        if (row < N_NODES) {
            __half2* hp = reinterpret_cast<__half2*>(hh + (long long)row * BN);
            hp[tc * 2 + 0] = __floats2half2_rn(acc[i][0], acc[i][1]);
            hp[tc * 2 + 1] = __floats2half2_rn(acc[i][2], acc[i][3]);
            if (BN == 128) {
                hp[tc * 2 + 32] = __floats2half2_rn(acc[i][4], acc[i][5]);
                hp[tc * 2 + 33] = __floats2half2_rn(acc[i][6], acc[i][7]);
            }
        }
    }
}

// ============================================================================
// Wave-per-node attention logits via shfl reduction. 4 nodes per 256-block.
// Reads fp16 h; math in f32.  NOTE: both F=128 and F=64 rows are n*64 units
// (half2 for F=128, half for F=64).
// ============================================================================
template <int H, int D>
__global__ __launch_bounds__(256)
void eler_wave(const __half* __restrict__ hh, const float* __restrict__ al,
               const float* __restrict__ ar, float* __restrict__ el,
               float* __restrict__ er) {
    constexpr int F   = H * D;
    constexpr int CPL = F / 64;
    constexpr int LPH = 64 / H;
    const int lane = threadIdx.x & 63;
    const int wid  = threadIdx.x >> 6;
    const int n    = blockIdx.x * 4 + wid;
    if (n >= N_NODES) return;

    float a, b;
    if (CPL == 2) {
        __half2 v2 = reinterpret_cast<const __half2*>(hh)[(long long)n * 64 + lane];
        float2 v = __half22float2(v2);
        float2 A = *reinterpret_cast<const float2*>(al + lane * 2);
        float2 B = *reinterpret_cast<const float2*>(ar + lane * 2);
        a = v.x * A.x + v.y * A.y;
        b = v.x * B.x + v.y * B.y;
    } else {
        float v = __half2float(hh[(long long)n * 64 + lane]);
        a = v * al[lane];
        b = v * ar[lane];
    }
#pragma unroll
    for (int off = 1; off < LPH; off <<= 1) {
        a += __shfl_xor(a, off);
        b += __shfl_xor(b, off);
    }
    if ((lane & (LPH - 1)) == 0) {
        int hh2 = lane / LPH;
        el[n * H + hh2] = a;
        er[n * H + hh2] = b;
    }
}

// ============================================================================
// CSR build (once per call; graph shared by all 3 layers)
// ============================================================================
__global__ void zero_counts(int* __restrict__ counts) {
    int i = blockIdx.x * blockDim.x + threadIdx.x;
    if (i < N_NODES) counts[i] = 0;
}

__global__ void hist_kernel(const int* __restrict__ dst, int* __restrict__ counts) {
    int e = blockIdx.x * blockDim.x + threadIdx.x;
    if (e < N_EDGES) atomicAdd(counts + dst[e], 1);
}

__global__ __launch_bounds__(1024)
void scan_local(const int* __restrict__ counts, int* __restrict__ row_ptr,
                int* __restrict__ bsum) {
    __shared__ int wsums[16];
    const int tid = threadIdx.x, lane = tid & 63, wid = tid >> 6;
    const int i = blockIdx.x * 1024 + tid;
    int v = (i < N_NODES) ? counts[i] : 0;
    int incl = v;
#pragma unroll
    for (int off = 1; off < 64; off <<= 1) {
        int t = __shfl_up(incl, off);
        if (lane >= off) incl += t;
    }
    if (lane == 63) wsums[wid] = incl;
    __syncthreads();
    if (wid == 0) {
        int ws = (lane < 16) ? wsums[lane] : 0;
#pragma unroll
        for (int off = 1; off < 16; off <<= 1) {
            int t = __shfl_up(ws, off);
            if (lane >= off) ws += t;
        }
        if (lane < 16) wsums[lane] = ws;
        if (lane == 15) bsum[blockIdx.x] = ws;
    }
    __syncthreads();
    int woff = (wid > 0) ? wsums[wid - 1] : 0;
    if (i < N_NODES) row_ptr[i] = woff + incl - v;
}

__global__ void scan_bsums(int* __restrict__ bsum, int* __restrict__ row_ptr, int nb) {
    const int lane = threadIdx.x;
    int v = (lane < nb) ? bsum[lane] : 0;
    int incl = v;
#pragma unroll
    for (int off = 1; off < 64; off <<= 1) {
        int t = __shfl_up(incl, off);
        if (lane >= off) incl += t;
    }
    if (lane < nb) bsum[lane] = incl - v;
    if (lane == 63) row_ptr[N_NODES] = incl;
}

__global__ void scan_add(int* __restrict__ row_ptr, const int* __restrict__ bsum,
                         int* __restrict__ cursor) {
    int i = blockIdx.x * blockDim.x + threadIdx.x;
    if (i < N_NODES) {
        int r = row_ptr[i] + bsum[i >> 10];
        row_ptr[i] = r;
        cursor[i]  = r;
    }
}

__global__ void scatter_kernel(const int* __restrict__ src, const int* __restrict__ dst,
                               int* __restrict__ cursor, int* __restrict__ sorted_src) {
    int e = blockIdx.x * blockDim.x + threadIdx.x;
    if (e >= N_EDGES) return;
    int pos = atomicAdd(cursor + dst[e], 1);
    sorted_src[pos] = src[e];
}

// ============================================================================
// Wave-per-node aggregate, 4 heads (F=128), dedup'd weights, fp16 h rows.
// Lane l (head hh=l>>4) owns weights for edges ee ≡ l (mod 16) of its head;
// reader pulls weight(ee,hc) from lane (ee&15)|(hc<<4), register ee>>4.
// ============================================================================
__global__ __launch_bounds__(256)
void gat_agg_h4(const int* __restrict__ row_ptr, const int* __restrict__ sorted_src,
                const float* __restrict__ el, const float* __restrict__ er,
                const __half* __restrict__ hh, const float* __restrict__ bias,
                float* __restrict__ out, int do_relu) {
    const __half2* hh2 = reinterpret_cast<const __half2*>(hh);
    const int lane = threadIdx.x & 63;
    const int wid  = threadIdx.x >> 6;
    const int n    = blockIdx.x * 4 + wid;
    if (n >= N_NODES) return;

    const int start = row_ptr[n];
    const int deg   = row_ptr[n + 1] - start;

    const float4 ern = *reinterpret_cast<const float4*>(er + n * 4);

    // ---- phase 1: per-head max (no exp) ----
    float m0 = -FLT_MAX, m1 = -FLT_MAX, m2 = -FLT_MAX, m3 = -FLT_MAX;
    for (int base = 0; base < deg; base += 64) {
        int idx = base + lane;
        if (idx < deg) {
            int sr = sorted_src[start + idx];
            float4 e4 = *reinterpret_cast<const float4*>(el + sr * 4);
            float v0 = e4.x + ern.x; v0 = (v0 >= 0.f) ? v0 : 0.2f * v0;
            float v1 = e4.y + ern.y; v1 = (v1 >= 0.f) ? v1 : 0.2f * v1;
            float v2 = e4.z + ern.z; v2 = (v2 >= 0.f) ? v2 : 0.2f * v2;
            float v3 = e4.w + ern.w; v3 = (v3 >= 0.f) ? v3 : 0.2f * v3;
            m0 = fmaxf(m0, v0); m1 = fmaxf(m1, v1);
            m2 = fmaxf(m2, v2); m3 = fmaxf(m3, v3);
        }
    }
#pragma unroll
    for (int off = 1; off < 64; off <<= 1) {
        m0 = fmaxf(m0, __shfl_xor(m0, off));
        m1 = fmaxf(m1, __shfl_xor(m1, off));
        m2 = fmaxf(m2, __shfl_xor(m2, off));
        m3 = fmaxf(m3, __shfl_xor(m3, off));
    }

    const int hc = lane >> 4;
    const int hsh = hc << 4;
    const float ma  = (hc & 2) ? m2 : m0;
    const float mb  = (hc & 2) ? m3 : m1;
    const float m_c = (hc & 1) ? mb : ma;
    const float ea  = (hc & 2) ? ern.z : ern.x;
    const float eb  = (hc & 2) ? ern.w : ern.y;
    const float erc = (hc & 1) ? eb : ea;

    float acc0 = 0.f, acc1 = 0.f, ssum = 0.f;

#define AGG2(EE)                                                                      \
    {                                                                                 \
        int   se = __shfl(sr, (EE));                                                  \
        float we = __shfl(w[(EE) >> 4], ((EE) & 15) | hsh);                           \
        float2 hv = __half22float2(hh2[(long long)se * 64 + lane]);                   \
        acc0 += we * hv.x; acc1 += we * hv.y; ssum += we;                             \
    }

    for (int base = 0; base < deg; base += 64) {
        int cnt = min(64, deg - base);
        int sr = 0;
        if (lane < cnt) sr = sorted_src[start + base + lane];

        // weights for my head's 4 edges: ee = (lane&15) + 16k
        float w[4];
#pragma unroll
        for (int k = 0; k < 4; ++k) {
            int ee = (lane & 15) + 16 * k;
            int sk = __shfl(sr, ee);
            float v = el[sk * 4 + hc] + erc;
            v = (v >= 0.f) ? v : 0.2f * v;
            w[k] = (ee < cnt) ? __expf(v - m_c) : 0.f;
        }

        if (cnt == 64) {
#pragma unroll 8
            for (int ee = 0; ee < 64; ++ee) AGG2(ee)
        } else {
#pragma unroll
            for (int k = 0; k < 4; ++k) {
                int lim = min(16, cnt - 16 * k);
                for (int e2 = 0; e2 < lim; ++e2) {
                    int   se = __shfl(sr, 16 * k + e2);
                    float we = __shfl(w[k], e2 | hsh);
                    float2 hv = __half22float2(hh2[(long long)se * 64 + lane]);
                    acc0 += we * hv.x; acc1 += we * hv.y; ssum += we;
                }
            }
        }
    }
#undef AGG2

    float inv = (ssum > 0.f) ? 1.f / ssum : 0.f;
    int c = lane * 2;
    float o0 = acc0 * inv + bias[c];
    float o1 = acc1 * inv + bias[c + 1];
    if (do_relu) { o0 = fmaxf(o0, 0.f); o1 = fmaxf(o1, 0.f); }
    *reinterpret_cast<float2*>(out + (long long)n * 128 + c) = make_float2(o0, o1);
}

// ---- single-head (F=64) variant, fp16 h ----
__global__ __launch_bounds__(256)
void gat_agg_h1(const int* __restrict__ row_ptr, const int* __restrict__ sorted_src,
                const float* __restrict__ el, const float* __restrict__ er,
                const __half* __restrict__ hh, const float* __restrict__ bias,
                float* __restrict__ out, int do_relu) {
    const int lane = threadIdx.x & 63;
    const int wid  = threadIdx.x >> 6;
    const int n    = blockIdx.x * 4 + wid;
    if (n >= N_NODES) return;

    const int start = row_ptr[n];
    const int deg   = row_ptr[n + 1] - start;
    const float ern = er[n];

    float m = -FLT_MAX;
    for (int base = 0; base < deg; base += 64) {
        int idx = base + lane;
        if (idx < deg) {
            int sr = sorted_src[start + idx];
            float v = el[sr] + ern;
            v = (v >= 0.f) ? v : 0.2f * v;
            m = fmaxf(m, v);
        }
    }
#pragma unroll
    for (int off = 1; off < 64; off <<= 1) m = fmaxf(m, __shfl_xor(m, off));

    float acc = 0.f, ssum = 0.f;

#define AGG1(EE)                                                       \
    {                                                                  \
        int   se = __shfl(sr, (EE));                                   \
        float we = __shfl(w, (EE));                                    \
        acc += we * __half2float(hh[(long long)se * 64 + lane]);       \
        ssum += we;                                                    \
    }

    for (int base = 0; base < deg; base += 64) {
        int cnt = min(64, deg - base);
        int sr = 0;
        float w = 0.f;
        if (lane < cnt) {
            sr = sorted_src[start + base + lane];
            float v = el[sr] + ern;
            v = (v >= 0.f) ? v : 0.2f * v;
            w = __expf(v - m);
        }
        if (cnt == 64) {
#pragma unroll 8
            for (int ee = 0; ee < 64; ++ee) AGG1(ee)
        } else {
            for (int ee = 0; ee < cnt; ++ee) AGG1(ee)
        }
    }
#undef AGG1

    float inv = (ssum > 0.f) ? 1.f / ssum : 0.f;
    float o = acc * inv + bias[lane];
    if (do_relu) o = fmaxf(o, 0.f);
    out[(long long)n * 64 + lane] = o;
}

// ============================================================================
// host-side layer driver
// ============================================================================
static void run_layer(const float* x, int Fin, const float* W, const float* al,
                      const float* ar, const float* bias, int H, int D,
                      const int* row_ptr, const int* sorted_src,
                      __half* hh, float* el, float* er, float* xnext, int do_relu,
                      hipStream_t stream) {
    const int gblocks = (N_NODES + 127) / 128;
    const int nblocks = (N_NODES + 3) / 4;
    if (H == 4) {
        gemm_tile<128><<<gblocks, 256, 0, stream>>>(x, W, hh, Fin);
        eler_wave<4, 32><<<nblocks, 256, 0, stream>>>(hh, al, ar, el, er);
        gat_agg_h4<<<nblocks, 256, 0, stream>>>(row_ptr, sorted_src, el, er, hh,
                                                bias, xnext, do_relu);
    } else {
        gemm_tile<64><<<gblocks, 256, 0, stream>>>(x, W, hh, Fin);
        eler_wave<1, 64><<<nblocks, 256, 0, stream>>>(hh, al, ar, el, er);
        gat_agg_h1<<<nblocks, 256, 0, stream>>>(row_ptr, sorted_src, el, er, hh,
                                                bias, xnext, do_relu);
    }
}

extern "C" void kernel_launch(void* const* d_in, const int* in_sizes, int n_in,
                              void* d_out, int out_size, void* d_ws, size_t ws_size,
                              hipStream_t stream) {
    const float* feat = (const float*)d_in[0];
    const int*   src  = (const int*)d_in[1];
    const int*   dst  = (const int*)d_in[2];
    const float* W1  = (const float*)d_in[3];
    const float* al1 = (const float*)d_in[4];
    const float* ar1 = (const float*)d_in[5];
    const float* b1  = (const float*)d_in[6];
    const float* W2  = (const float*)d_in[7];
    const float* al2 = (const float*)d_in[8];
    const float* ar2 = (const float*)d_in[9];
    const float* b2  = (const float*)d_in[10];
    const float* W3  = (const float*)d_in[11];
    const float* al3 = (const float*)d_in[12];
    const float* ar3 = (const float*)d_in[13];
    const float* b3  = (const float*)d_in[14];

    // workspace carve-up
    float* ws = (float*)d_ws;
    __half* hh  = (__half*)ws;                          // N*128 halves (in N*64 f32 slot)
    float* xbuf = ws + (long long)N_NODES * 64;         // N*128
    float* el   = xbuf + (long long)N_NODES * 128;      // N*4
    float* er   = el   + (long long)N_NODES * 4;        // N*4
    int* counts     = (int*)(er + (long long)N_NODES * 4);  // N
    int* row_ptr    = counts  + N_NODES;                    // N+1
    int* cursor     = row_ptr + N_NODES + 1;                // N
    int* sorted_src = cursor  + N_NODES;                    // E
    int* bsum       = sorted_src + N_EDGES;                 // 64

    // ---- build CSR once (graph shared by all 3 layers) ----
    const int SB = (N_NODES + 1023) / 1024;   // 49
    zero_counts<<<(N_NODES + 255) / 256, 256, 0, stream>>>(counts);
    hist_kernel<<<(N_EDGES + 255) / 256, 256, 0, stream>>>(dst, counts);
    scan_local<<<SB, 1024, 0, stream>>>(counts, row_ptr, bsum);
    scan_bsums<<<1, 64, 0, stream>>>(bsum, row_ptr, SB);
    scan_add<<<(N_NODES + 255) / 256, 256, 0, stream>>>(row_ptr, bsum, cursor);
    scatter_kernel<<<(N_EDGES + 255) / 256, 256, 0, stream>>>(src, dst, cursor, sorted_src);

    // layer 1: 256 -> 4x32, relu
    run_layer(feat, 256, W1, al1, ar1, b1, 4, 32, row_ptr, sorted_src,
              hh, el, er, xbuf, 1, stream);
    // layer 2: 128 -> 4x32, relu
    run_layer(xbuf, 128, W2, al2, ar2, b2, 4, 32, row_ptr, sorted_src,
              hh, el, er, xbuf, 1, stream);
    // layer 3: 128 -> 1x64, no relu, straight to d_out
    run_layer(xbuf, 128, W3, al3, ar3, b3, 1, 64, row_ptr, sorted_src,
              hh, el, er, (float*)d_out, 0, stream);
}

// Round 8
// 399.753 us; speedup vs baseline: 9.8691x; 1.0774x over previous
//
#include <hip/hip_runtime.h>
#include <hip/hip_fp16.h>
#include <cfloat>

#define N_NODES 50000
#define N_EDGES 800000

// ============================================================================
// Register-tiled GEMM + fused attention-logit epilogue.
// h[N,BN] = x[N,Fin] @ W[Fin,BN] (written fp16);
// el[n,h] = sum_d h*al, er likewise (f32), reduced via 16-lane shfl.
// ============================================================================
template <int BN>
__global__ __launch_bounds__(256)
void gemm_tile(const float* __restrict__ x, const float* __restrict__ W,
               __half* __restrict__ hh, const float* __restrict__ al,
               const float* __restrict__ ar, float* __restrict__ el,
               float* __restrict__ er, int Fin) {
    constexpr int BM = 128, BK = 32;
    constexpr int CN = (BN == 128) ? 8 : 4;
    constexpr int NF = BN * BK / 256;
    constexpr int NV = NF / 4;
    __shared__ float xs[BK][BM];
    __shared__ float ws[BK][BN];

    const int t  = threadIdx.x;
    const int r0 = blockIdx.x * BM;
    const int tr = t / 16, tc = t % 16;

    const int xrow  = t >> 1;
    const int xkoff = (t & 1) * 16;
    const bool xok  = (r0 + xrow) < N_NODES;
    const float* xrp = x + (long long)(r0 + xrow) * Fin;
    const int wk  = t >> 3;
    const int wcb = (t & 7) * NF;

    float acc[8][CN];
#pragma unroll
    for (int i = 0; i < 8; ++i)
#pragma unroll
        for (int j = 0; j < CN; ++j) acc[i][j] = 0.f;

    for (int k0 = 0; k0 < Fin; k0 += BK) {
#pragma unroll
        for (int j = 0; j < 4; ++j) {
            float4 v = make_float4(0.f, 0.f, 0.f, 0.f);
            if (xok) v = *reinterpret_cast<const float4*>(xrp + k0 + xkoff + 4 * j);
            xs[xkoff + 4 * j + 0][xrow] = v.x;
            xs[xkoff + 4 * j + 1][xrow] = v.y;
            xs[xkoff + 4 * j + 2][xrow] = v.z;
            xs[xkoff + 4 * j + 3][xrow] = v.w;
        }
#pragma unroll
        for (int j = 0; j < NV; ++j) {
            float4 v = *reinterpret_cast<const float4*>(W + (long long)(k0 + wk) * BN + wcb + 4 * j);
            *reinterpret_cast<float4*>(&ws[wk][wcb + 4 * j]) = v;
        }
        __syncthreads();

#pragma unroll
        for (int kk = 0; kk < BK; ++kk) {
            float ra[8], rb[CN];
            float4 a0 = *reinterpret_cast<const float4*>(&xs[kk][tr * 4]);
            float4 a1 = *reinterpret_cast<const float4*>(&xs[kk][tr * 4 + 64]);
            ra[0] = a0.x; ra[1] = a0.y; ra[2] = a0.z; ra[3] = a0.w;
            ra[4] = a1.x; ra[5] = a1.y; ra[6] = a1.z; ra[7] = a1.w;
            float4 b0 = *reinterpret_cast<const float4*>(&ws[kk][tc * 4]);
            rb[0] = b0.x; rb[1] = b0.y; rb[2] = b0.z; rb[3] = b0.w;
            if (BN == 128) {
                float4 b1 = *reinterpret_cast<const float4*>(&ws[kk][tc * 4 + 64]);
                rb[4] = b1.x; rb[5] = b1.y; rb[6] = b1.z; rb[7] = b1.w;
            }
#pragma unroll
            for (int i = 0; i < 8; ++i)
#pragma unroll
                for (int j = 0; j < CN; ++j) acc[i][j] += ra[i] * rb[j];
        }
        __syncthreads();
    }

    // ---- load al/ar slices for this thread's columns ----
    float4 alA = *reinterpret_cast<const float4*>(al + tc * 4);
    float4 arA = *reinterpret_cast<const float4*>(ar + tc * 4);
    float4 alB = make_float4(0.f, 0.f, 0.f, 0.f), arB = alB;
    if (BN == 128) {
        alB = *reinterpret_cast<const float4*>(al + tc * 4 + 64);
        arB = *reinterpret_cast<const float4*>(ar + tc * 4 + 64);
    }

#pragma unroll
    for (int i = 0; i < 8; ++i) {
        int row = r0 + tr * 4 + (i / 4) * 64 + (i % 4);
        if (row >= N_NODES) continue;

        // h write (fp16)
        __half2* hp = reinterpret_cast<__half2*>(hh + (long long)row * BN);
        hp[tc * 2 + 0] = __floats2half2_rn(acc[i][0], acc[i][1]);
        hp[tc * 2 + 1] = __floats2half2_rn(acc[i][2], acc[i][3]);
        if (BN == 128) {
            hp[tc * 2 + 32] = __floats2half2_rn(acc[i][4], acc[i][5]);
            hp[tc * 2 + 33] = __floats2half2_rn(acc[i][6], acc[i][7]);
        }

        // fused el/er: partial over this thread's 4 cols per head-slice
        float ela = acc[i][0] * alA.x + acc[i][1] * alA.y + acc[i][2] * alA.z + acc[i][3] * alA.w;
        float era = acc[i][0] * arA.x + acc[i][1] * arA.y + acc[i][2] * arA.z + acc[i][3] * arA.w;
        float elb = 0.f, erb = 0.f;
        if (BN == 128) {
            elb = acc[i][4] * alB.x + acc[i][5] * alB.y + acc[i][6] * alB.z + acc[i][7] * alB.w;
            erb = acc[i][4] * arB.x + acc[i][5] * arB.y + acc[i][6] * arB.z + acc[i][7] * arB.w;
        }
        if (BN == 128) {
            // reduce over tc within 8-groups (heads: a = tc/8, b = tc/8 + 2)
#pragma unroll
            for (int off = 1; off < 8; off <<= 1) {
                ela += __shfl_xor(ela, off);
                era += __shfl_xor(era, off);
                elb += __shfl_xor(elb, off);
                erb += __shfl_xor(erb, off);
            }
            if ((tc & 7) == 0) {
                int ha = tc >> 3;          // 0 or 1
                el[row * 4 + ha]     = ela;
                er[row * 4 + ha]     = era;
                el[row * 4 + ha + 2] = elb;
                er[row * 4 + ha + 2] = erb;
            }
        } else {
            // single head: reduce over all 16 tc
#pragma unroll
            for (int off = 1; off < 16; off <<= 1) {
                ela += __shfl_xor(ela, off);
                era += __shfl_xor(era, off);
            }
            if (tc == 0) {
                el[row] = ela;
                er[row] = era;
            }
        }
    }
}

// ============================================================================
// CSR build (once per call; graph shared by all 3 layers)
// ============================================================================
__global__ void zero_counts(int* __restrict__ counts) {
    int i = blockIdx.x * blockDim.x + threadIdx.x;
    if (i < N_NODES) counts[i] = 0;
}

__global__ void hist_kernel(const int* __restrict__ dst, int* __restrict__ counts) {
    int e = blockIdx.x * blockDim.x + threadIdx.x;
    if (e < N_EDGES) atomicAdd(counts + dst[e], 1);
}

__global__ __launch_bounds__(1024)
void scan_local(const int* __restrict__ counts, int* __restrict__ row_ptr,
                int* __restrict__ bsum) {
    __shared__ int wsums[16];
    const int tid = threadIdx.x, lane = tid & 63, wid = tid >> 6;
    const int i = blockIdx.x * 1024 + tid;
    int v = (i < N_NODES) ? counts[i] : 0;
    int incl = v;
#pragma unroll
    for (int off = 1; off < 64; off <<= 1) {
        int t = __shfl_up(incl, off);
        if (lane >= off) incl += t;
    }
    if (lane == 63) wsums[wid] = incl;
    __syncthreads();
    if (wid == 0) {
        int ws = (lane < 16) ? wsums[lane] : 0;
#pragma unroll
        for (int off = 1; off < 16; off <<= 1) {
            int t = __shfl_up(ws, off);
            if (lane >= off) ws += t;
        }
        if (lane < 16) wsums[lane] = ws;
        if (lane == 15) bsum[blockIdx.x] = ws;
    }
    __syncthreads();
    int woff = (wid > 0) ? wsums[wid - 1] : 0;
    if (i < N_NODES) row_ptr[i] = woff + incl - v;
}

__global__ void scan_bsums(int* __restrict__ bsum, int* __restrict__ row_ptr, int nb) {
    const int lane = threadIdx.x;
    int v = (lane < nb) ? bsum[lane] : 0;
    int incl = v;
#pragma unroll
    for (int off = 1; off < 64; off <<= 1) {
        int t = __shfl_up(incl, off);
        if (lane >= off) incl += t;
    }
    if (lane < nb) bsum[lane] = incl - v;
    if (lane == 63) row_ptr[N_NODES] = incl;
}

__global__ void scan_add(int* __restrict__ row_ptr, const int* __restrict__ bsum,
                         int* __restrict__ cursor) {
    int i = blockIdx.x * blockDim.x + threadIdx.x;
    if (i < N_NODES) {
        int r = row_ptr[i] + bsum[i >> 10];
        row_ptr[i] = r;
        cursor[i]  = r;
    }
}

__global__ void scatter_kernel(const int* __restrict__ src, const int* __restrict__ dst,
                               int* __restrict__ cursor, int* __restrict__ sorted_src) {
    int e = blockIdx.x * blockDim.x + threadIdx.x;
    if (e >= N_EDGES) return;
    int pos = atomicAdd(cursor + dst[e], 1);
    sorted_src[pos] = src[e];
}

// ============================================================================
// Wave-per-node aggregate, 4 heads (F=128), dedup'd weights, fp16 h, NO max
// pass (softmax is shift-invariant; |logit| is O(1) by weight scale, exp safe).
// Lane l (head l>>4) owns weights for edges ee ≡ l (mod 16) of its head;
// reader pulls weight(ee,hc) from lane (ee&15)|(hc<<4), register ee>>4.
// ============================================================================
__global__ __launch_bounds__(256)
void gat_agg_h4(const int* __restrict__ row_ptr, const int* __restrict__ sorted_src,
                const float* __restrict__ el, const float* __restrict__ er,
                const __half* __restrict__ hh, const float* __restrict__ bias,
                float* __restrict__ out, int do_relu) {
    const __half2* hh2 = reinterpret_cast<const __half2*>(hh);
    const int lane = threadIdx.x & 63;
    const int wid  = threadIdx.x >> 6;
    const int n    = blockIdx.x * 4 + wid;
    if (n >= N_NODES) return;

    const int start = row_ptr[n];
    const int deg   = row_ptr[n + 1] - start;

    const float4 ern = *reinterpret_cast<const float4*>(er + n * 4);

    const int hc = lane >> 4;
    const int hsh = hc << 4;
    const float ea  = (hc & 2) ? ern.z : ern.x;
    const float eb  = (hc & 2) ? ern.w : ern.y;
    const float erc = (hc & 1) ? eb : ea;

    float acc0 = 0.f, acc1 = 0.f, ssum = 0.f;

#define AGG2(EE)                                                                      \
    {                                                                                 \
        int   se = __shfl(sr, (EE));                                                  \
        float we = __shfl(w[(EE) >> 4], ((EE) & 15) | hsh);                           \
        float2 hv = __half22float2(hh2[(long long)se * 64 + lane]);                   \
        acc0 += we * hv.x; acc1 += we * hv.y; ssum += we;                             \
    }

    for (int base = 0; base < deg; base += 64) {
        int cnt = min(64, deg - base);
        int sr = 0;
        if (lane < cnt) sr = sorted_src[start + base + lane];

        // weights for my head's 4 edges: ee = (lane&15) + 16k
        float w[4];
#pragma unroll
        for (int k = 0; k < 4; ++k) {
            int ee = (lane & 15) + 16 * k;
            int sk = __shfl(sr, ee);
            float v = el[sk * 4 + hc] + erc;
            v = (v >= 0.f) ? v : 0.2f * v;
            w[k] = (ee < cnt) ? __expf(v) : 0.f;
        }

        if (cnt == 64) {
#pragma unroll 8
            for (int ee = 0; ee < 64; ++ee) AGG2(ee)
        } else {
#pragma unroll
            for (int k = 0; k < 4; ++k) {
                int lim = min(16, cnt - 16 * k);
                for (int e2 = 0; e2 < lim; ++e2) {
                    int   se = __shfl(sr, 16 * k + e2);
                    float we = __shfl(w[k], e2 | hsh);
                    float2 hv = __half22float2(hh2[(long long)se * 64 + lane]);
                    acc0 += we * hv.x; acc1 += we * hv.y; ssum += we;
                }
            }
        }
    }
#undef AGG2

    float inv = (ssum > 0.f) ? 1.f / ssum : 0.f;
    int c = lane * 2;
    float o0 = acc0 * inv + bias[c];
    float o1 = acc1 * inv + bias[c + 1];
    if (do_relu) { o0 = fmaxf(o0, 0.f); o1 = fmaxf(o1, 0.f); }
    *reinterpret_cast<float2*>(out + (long long)n * 128 + c) = make_float2(o0, o1);
}

// ---- single-head (F=64) variant, fp16 h, no max pass ----
__global__ __launch_bounds__(256)
void gat_agg_h1(const int* __restrict__ row_ptr, const int* __restrict__ sorted_src,
                const float* __restrict__ el, const float* __restrict__ er,
                const __half* __restrict__ hh, const float* __restrict__ bias,
                float* __restrict__ out, int do_relu) {
    const int lane = threadIdx.x & 63;
    const int wid  = threadIdx.x >> 6;
    const int n    = blockIdx.x * 4 + wid;
    if (n >= N_NODES) return;

    const int start = row_ptr[n];
    const int deg   = row_ptr[n + 1] - start;
    const float ern = er[n];

    float acc = 0.f, ssum = 0.f;

#define AGG1(EE)                                                       \
    {                                                                  \
        int   se = __shfl(sr, (EE));                                   \
        float we = __shfl(w, (EE));                                    \
        acc += we * __half2float(hh[(long long)se * 64 + lane]);       \
        ssum += we;                                                    \
    }

    for (int base = 0; base < deg; base += 64) {
        int cnt = min(64, deg - base);
        int sr = 0;
        float w = 0.f;
        if (lane < cnt) {
            sr = sorted_src[start + base + lane];
            float v = el[sr] + ern;
            v = (v >= 0.f) ? v : 0.2f * v;
            w = __expf(v);
        }
        if (cnt == 64) {
#pragma unroll 8
            for (int ee = 0; ee < 64; ++ee) AGG1(ee)
        } else {
            for (int ee = 0; ee < cnt; ++ee) AGG1(ee)
        }
    }
#undef AGG1

    float inv = (ssum > 0.f) ? 1.f / ssum : 0.f;
    float o = acc * inv + bias[lane];
    if (do_relu) o = fmaxf(o, 0.f);
    out[(long long)n * 64 + lane] = o;
}

// ============================================================================
// host-side layer driver
// ============================================================================
static void run_layer(const float* x, int Fin, const float* W, const float* al,
                      const float* ar, const float* bias, int H, int D,
                      const int* row_ptr, const int* sorted_src,
                      __half* hh, float* el, float* er, float* xnext, int do_relu,
                      hipStream_t stream) {
    const int gblocks = (N_NODES + 127) / 128;
    const int nblocks = (N_NODES + 3) / 4;
    if (H == 4) {
        gemm_tile<128><<<gblocks, 256, 0, stream>>>(x, W, hh, al, ar, el, er, Fin);
        gat_agg_h4<<<nblocks, 256, 0, stream>>>(row_ptr, sorted_src, el, er, hh,
                                                bias, xnext, do_relu);
    } else {
        gemm_tile<64><<<gblocks, 256, 0, stream>>>(x, W, hh, al, ar, el, er, Fin);
        gat_agg_h1<<<nblocks, 256, 0, stream>>>(row_ptr, sorted_src, el, er, hh,
                                                bias, xnext, do_relu);
    }
}

extern "C" void kernel_launch(void* const* d_in, const int* in_sizes, int n_in,
                              void* d_out, int out_size, void* d_ws, size_t ws_size,
                              hipStream_t stream) {
    const float* feat = (const float*)d_in[0];
    const int*   src  = (const int*)d_in[1];
    const int*   dst  = (const int*)d_in[2];
    const float* W1  = (const float*)d_in[3];
    const float* al1 = (const float*)d_in[4];
    const float* ar1 = (const float*)d_in[5];
    const float* b1  = (const float*)d_in[6];
    const float* W2  = (const float*)d_in[7];
    const float* al2 = (const float*)d_in[8];
    const float* ar2 = (const float*)d_in[9];
    const float* b2  = (const float*)d_in[10];
    const float* W3  = (const float*)d_in[11];
    const float* al3 = (const float*)d_in[12];
    const float* ar3 = (const float*)d_in[13];
    const float* b3  = (const float*)d_in[14];

    // workspace carve-up
    float* ws = (float*)d_ws;
    __half* hh  = (__half*)ws;                          // N*128 halves (in N*64 f32 slot)
    float* xbuf = ws + (long long)N_NODES * 64;         // N*128
    float* el   = xbuf + (long long)N_NODES * 128;      // N*4
    float* er   = el   + (long long)N_NODES * 4;        // N*4
    int* counts     = (int*)(er + (long long)N_NODES * 4);  // N
    int* row_ptr    = counts  + N_NODES;                    // N+1
    int* cursor     = row_ptr + N_NODES + 1;                // N
    int* sorted_src = cursor  + N_NODES;                    // E
    int* bsum       = sorted_src + N_EDGES;                 // 64

    // ---- build CSR once (graph shared by all 3 layers) ----
    const int SB = (N_NODES + 1023) / 1024;   // 49
    zero_counts<<<(N_NODES + 255) / 256, 256, 0, stream>>>(counts);
    hist_kernel<<<(N_EDGES + 255) / 256, 256, 0, stream>>>(dst, counts);
    scan_local<<<SB, 1024, 0, stream>>>(counts, row_ptr, bsum);
    scan_bsums<<<1, 64, 0, stream>>>(bsum, row_ptr, SB);
    scan_add<<<(N_NODES + 255) / 256, 256, 0, stream>>>(row_ptr, bsum, cursor);
    scatter_kernel<<<(N_EDGES + 255) / 256, 256, 0, stream>>>(src, dst, cursor, sorted_src);

    // layer 1: 256 -> 4x32, relu
    run_layer(feat, 256, W1, al1, ar1, b1, 4, 32, row_ptr, sorted_src,
              hh, el, er, xbuf, 1, stream);
    // layer 2: 128 -> 4x32, relu
    run_layer(xbuf, 128, W2, al2, ar2, b2, 4, 32, row_ptr, sorted_src,
              hh, el, er, xbuf, 1, stream);
    // layer 3: 128 -> 1x64, no relu, straight to d_out
    run_layer(xbuf, 128, W3, al3, ar3, b3, 1, 64, row_ptr, sorted_src,
              hh, el, er, (float*)d_out, 0, stream);
}

// Round 9
// 335.316 us; speedup vs baseline: 11.7656x; 1.1922x over previous
//
#include <hip/hip_runtime.h>
#include <hip/hip_fp16.h>
#include <cfloat>

#define N_NODES 50000
#define N_EDGES 800000

// ============================================================================
// Register-tiled GEMM + fused attention-logit epilogue.
// h[N,BN] = x[N,Fin] @ W[Fin,BN] (written fp16);
// el[n,h] = sum_d h*al, er likewise (f32), reduced via 16-lane shfl.
// ============================================================================
template <int BN>
__global__ __launch_bounds__(256)
void gemm_tile(const float* __restrict__ x, const float* __restrict__ W,
               __half* __restrict__ hh, const float* __restrict__ al,
               const float* __restrict__ ar, float* __restrict__ el,
               float* __restrict__ er, int Fin) {
    constexpr int BM = 128, BK = 32;
    constexpr int CN = (BN == 128) ? 8 : 4;
    constexpr int NF = BN * BK / 256;
    constexpr int NV = NF / 4;
    __shared__ float xs[BK][BM];
    __shared__ float ws[BK][BN];

    const int t  = threadIdx.x;
    const int r0 = blockIdx.x * BM;
    const int tr = t / 16, tc = t % 16;

    const int xrow  = t >> 1;
    const int xkoff = (t & 1) * 16;
    const bool xok  = (r0 + xrow) < N_NODES;
    const float* xrp = x + (long long)(r0 + xrow) * Fin;
    const int wk  = t >> 3;
    const int wcb = (t & 7) * NF;

    float acc[8][CN];
#pragma unroll
    for (int i = 0; i < 8; ++i)
#pragma unroll
        for (int j = 0; j < CN; ++j) acc[i][j] = 0.f;

    for (int k0 = 0; k0 < Fin; k0 += BK) {
#pragma unroll
        for (int j = 0; j < 4; ++j) {
            float4 v = make_float4(0.f, 0.f, 0.f, 0.f);
            if (xok) v = *reinterpret_cast<const float4*>(xrp + k0 + xkoff + 4 * j);
            xs[xkoff + 4 * j + 0][xrow] = v.x;
            xs[xkoff + 4 * j + 1][xrow] = v.y;
            xs[xkoff + 4 * j + 2][xrow] = v.z;
            xs[xkoff + 4 * j + 3][xrow] = v.w;
        }
#pragma unroll
        for (int j = 0; j < NV; ++j) {
            float4 v = *reinterpret_cast<const float4*>(W + (long long)(k0 + wk) * BN + wcb + 4 * j);
            *reinterpret_cast<float4*>(&ws[wk][wcb + 4 * j]) = v;
        }
        __syncthreads();

#pragma unroll
        for (int kk = 0; kk < BK; ++kk) {
            float ra[8], rb[CN];
            float4 a0 = *reinterpret_cast<const float4*>(&xs[kk][tr * 4]);
            float4 a1 = *reinterpret_cast<const float4*>(&xs[kk][tr * 4 + 64]);
            ra[0] = a0.x; ra[1] = a0.y; ra[2] = a0.z; ra[3] = a0.w;
            ra[4] = a1.x; ra[5] = a1.y; ra[6] = a1.z; ra[7] = a1.w;
            float4 b0 = *reinterpret_cast<const float4*>(&ws[kk][tc * 4]);
            rb[0] = b0.x; rb[1] = b0.y; rb[2] = b0.z; rb[3] = b0.w;
            if (BN == 128) {
                float4 b1 = *reinterpret_cast<const float4*>(&ws[kk][tc * 4 + 64]);
                rb[4] = b1.x; rb[5] = b1.y; rb[6] = b1.z; rb[7] = b1.w;
            }
#pragma unroll
            for (int i = 0; i < 8; ++i)
#pragma unroll
                for (int j = 0; j < CN; ++j) acc[i][j] += ra[i] * rb[j];
        }
        __syncthreads();
    }

    float4 alA = *reinterpret_cast<const float4*>(al + tc * 4);
    float4 arA = *reinterpret_cast<const float4*>(ar + tc * 4);
    float4 alB = make_float4(0.f, 0.f, 0.f, 0.f), arB = alB;
    if (BN == 128) {
        alB = *reinterpret_cast<const float4*>(al + tc * 4 + 64);
        arB = *reinterpret_cast<const float4*>(ar + tc * 4 + 64);
    }

#pragma unroll
    for (int i = 0; i < 8; ++i) {
        int row = r0 + tr * 4 + (i / 4) * 64 + (i % 4);
        if (row >= N_NODES) continue;

        __half2* hp = reinterpret_cast<__half2*>(hh + (long long)row * BN);
        hp[tc * 2 + 0] = __floats2half2_rn(acc[i][0], acc[i][1]);
        hp[tc * 2 + 1] = __floats2half2_rn(acc[i][2], acc[i][3]);
        if (BN == 128) {
            hp[tc * 2 + 32] = __floats2half2_rn(acc[i][4], acc[i][5]);
            hp[tc * 2 + 33] = __floats2half2_rn(acc[i][6], acc[i][7]);
        }

        float ela = acc[i][0] * alA.x + acc[i][1] * alA.y + acc[i][2] * alA.z + acc[i][3] * alA.w;
        float era = acc[i][0] * arA.x + acc[i][1] * arA.y + acc[i][2] * arA.z + acc[i][3] * arA.w;
        float elb = 0.f, erb = 0.f;
        if (BN == 128) {
            elb = acc[i][4] * alB.x + acc[i][5] * alB.y + acc[i][6] * alB.z + acc[i][7] * alB.w;
            erb = acc[i][4] * arB.x + acc[i][5] * arB.y + acc[i][6] * arB.z + acc[i][7] * arB.w;
        }
        if (BN == 128) {
#pragma unroll
            for (int off = 1; off < 8; off <<= 1) {
                ela += __shfl_xor(ela, off);
                era += __shfl_xor(era, off);
                elb += __shfl_xor(elb, off);
                erb += __shfl_xor(erb, off);
            }
            if ((tc & 7) == 0) {
                int ha = tc >> 3;
                el[row * 4 + ha]     = ela;
                er[row * 4 + ha]     = era;
                el[row * 4 + ha + 2] = elb;
                er[row * 4 + ha + 2] = erb;
            }
        } else {
#pragma unroll
            for (int off = 1; off < 16; off <<= 1) {
                ela += __shfl_xor(ela, off);
                era += __shfl_xor(era, off);
            }
            if (tc == 0) {
                el[row] = ela;
                er[row] = era;
            }
        }
    }
}

// ============================================================================
// CSR build (once per call; graph shared by all 3 layers)
// ============================================================================
__global__ void zero_counts(int* __restrict__ counts) {
    int i = blockIdx.x * blockDim.x + threadIdx.x;
    if (i < N_NODES) counts[i] = 0;
}

__global__ void hist_kernel(const int* __restrict__ dst, int* __restrict__ counts) {
    int e = blockIdx.x * blockDim.x + threadIdx.x;
    if (e < N_EDGES) atomicAdd(counts + dst[e], 1);
}

__global__ __launch_bounds__(1024)
void scan_local(const int* __restrict__ counts, int* __restrict__ row_ptr,
                int* __restrict__ bsum) {
    __shared__ int wsums[16];
    const int tid = threadIdx.x, lane = tid & 63, wid = tid >> 6;
    const int i = blockIdx.x * 1024 + tid;
    int v = (i < N_NODES) ? counts[i] : 0;
    int incl = v;
#pragma unroll
    for (int off = 1; off < 64; off <<= 1) {
        int t = __shfl_up(incl, off);
        if (lane >= off) incl += t;
    }
    if (lane == 63) wsums[wid] = incl;
    __syncthreads();
    if (wid == 0) {
        int ws = (lane < 16) ? wsums[lane] : 0;
#pragma unroll
        for (int off = 1; off < 16; off <<= 1) {
            int t = __shfl_up(ws, off);
            if (lane >= off) ws += t;
        }
        if (lane < 16) wsums[lane] = ws;
        if (lane == 15) bsum[blockIdx.x] = ws;
    }
    __syncthreads();
    int woff = (wid > 0) ? wsums[wid - 1] : 0;
    if (i < N_NODES) row_ptr[i] = woff + incl - v;
}

__global__ void scan_bsums(int* __restrict__ bsum, int* __restrict__ row_ptr, int nb) {
    const int lane = threadIdx.x;
    int v = (lane < nb) ? bsum[lane] : 0;
    int incl = v;
#pragma unroll
    for (int off = 1; off < 64; off <<= 1) {
        int t = __shfl_up(incl, off);
        if (lane >= off) incl += t;
    }
    if (lane < nb) bsum[lane] = incl - v;
    if (lane == 63) row_ptr[N_NODES] = incl;
}

__global__ void scan_add(int* __restrict__ row_ptr, const int* __restrict__ bsum,
                         int* __restrict__ cursor) {
    int i = blockIdx.x * blockDim.x + threadIdx.x;
    if (i < N_NODES) {
        int r = row_ptr[i] + bsum[i >> 10];
        row_ptr[i] = r;
        cursor[i]  = r;
    }
}

__global__ void scatter_kernel(const int* __restrict__ src, const int* __restrict__ dst,
                               int* __restrict__ cursor, int* __restrict__ sorted_src) {
    int e = blockIdx.x * blockDim.x + threadIdx.x;
    if (e >= N_EDGES) return;
    int pos = atomicAdd(cursor + dst[e], 1);
    sorted_src[pos] = src[e];
}

// ============================================================================
// Wave-per-node aggregate, 4 heads (F=128), fp16 h, no max pass.
// 2 EDGES PER ITERATION: halves of the wave (lane>>5) each own one edge of a
// pair; each lane covers 4 cols via an 8B half4 load. Weight owners unchanged
// (lane l computes head l>>4 for edges ee ≡ l mod 16); pair indexing keeps the
// weight register index static ((2it+b)>>4 == it>>3, lane-independent; k-group
// nesting makes it compile-time). Halves merged via shfl_xor(32) at the end.
// ============================================================================
__global__ __launch_bounds__(256)
void gat_agg_h4(const int* __restrict__ row_ptr, const int* __restrict__ sorted_src,
                const float* __restrict__ el, const float* __restrict__ er,
                const __half* __restrict__ hh, const float* __restrict__ bias,
                float* __restrict__ out, int do_relu) {
    struct half4 { __half2 a, b; };
    const half4* hh4 = reinterpret_cast<const half4*>(hh);
    const int lane = threadIdx.x & 63;
    const int wid  = threadIdx.x >> 6;
    const int n    = blockIdx.x * 4 + wid;
    if (n >= N_NODES) return;

    const int start = row_ptr[n];
    const int deg   = row_ptr[n + 1] - start;

    const float4 ern = *reinterpret_cast<const float4*>(er + n * 4);

    // owner role: head ho = lane>>4, edges ee = (lane&15) + 16k
    const int ho = lane >> 4;
    const float eoa = (ho & 2) ? ern.z : ern.x;
    const float eob = (ho & 2) ? ern.w : ern.y;
    const float ero = (ho & 1) ? eob : eoa;

    // reader role: cols c0 = (lane&31)*4, head hr = (lane&31)>>3
    const int l5      = lane & 31;
    const int hr      = l5 >> 3;
    const int hsh     = hr << 4;
    const int half_id = lane >> 5;

    float a0 = 0.f, a1 = 0.f, a2 = 0.f, a3 = 0.f, ssum = 0.f;

    for (int base = 0; base < deg; base += 64) {
        int cnt = min(64, deg - base);
        int sr = 0;
        if (lane < cnt) sr = sorted_src[start + base + lane];

        float w[4];
#pragma unroll
        for (int k = 0; k < 4; ++k) {
            int ee = (lane & 15) + 16 * k;
            int sk = __shfl(sr, ee);
            float v = el[sk * 4 + ho] + ero;
            v = (v >= 0.f) ? v : 0.2f * v;
            w[k] = (ee < cnt) ? __expf(v) : 0.f;
        }

#pragma unroll
        for (int k = 0; k < 4; ++k) {
            int rem = cnt - 16 * k;
            if (rem > 0) {
                int pairs = (min(rem, 16) + 1) >> 1;
#pragma unroll 4
                for (int it = 0; it < pairs; ++it) {
                    int e0 = 16 * k + 2 * it + half_id;
                    int   se = __shfl(sr, e0);
                    float we = __shfl(w[k], (e0 & 15) | hsh);
                    half4 hv = hh4[(long long)se * 32 + l5];
                    float2 va = __half22float2(hv.a);
                    float2 vb = __half22float2(hv.b);
                    a0 += we * va.x; a1 += we * va.y;
                    a2 += we * vb.x; a3 += we * vb.y;
                    ssum += we;
                }
            }
        }
    }

    // merge the two halves (same cols, same head)
    a0 += __shfl_xor(a0, 32); a1 += __shfl_xor(a1, 32);
    a2 += __shfl_xor(a2, 32); a3 += __shfl_xor(a3, 32);
    ssum += __shfl_xor(ssum, 32);

    if (lane < 32) {
        float inv = (ssum > 0.f) ? 1.f / ssum : 0.f;
        int c0 = l5 * 4;
        float4 b4 = *reinterpret_cast<const float4*>(bias + c0);
        float o0 = a0 * inv + b4.x;
        float o1 = a1 * inv + b4.y;
        float o2 = a2 * inv + b4.z;
        float o3 = a3 * inv + b4.w;
        if (do_relu) {
            o0 = fmaxf(o0, 0.f); o1 = fmaxf(o1, 0.f);
            o2 = fmaxf(o2, 0.f); o3 = fmaxf(o3, 0.f);
        }
        *reinterpret_cast<float4*>(out + (long long)n * 128 + c0) = make_float4(o0, o1, o2, o3);
    }
}

// ---- single-head (F=64) variant, fp16 h, 2 edges/iter ----
__global__ __launch_bounds__(256)
void gat_agg_h1(const int* __restrict__ row_ptr, const int* __restrict__ sorted_src,
                const float* __restrict__ el, const float* __restrict__ er,
                const __half* __restrict__ hh, const float* __restrict__ bias,
                float* __restrict__ out, int do_relu) {
    const __half2* hh2 = reinterpret_cast<const __half2*>(hh);
    const int lane = threadIdx.x & 63;
    const int wid  = threadIdx.x >> 6;
    const int n    = blockIdx.x * 4 + wid;
    if (n >= N_NODES) return;

    const int start = row_ptr[n];
    const int deg   = row_ptr[n + 1] - start;
    const float ern = er[n];

    const int l5      = lane & 31;
    const int half_id = lane >> 5;

    float a0 = 0.f, a1 = 0.f, ssum = 0.f;

    for (int base = 0; base < deg; base += 64) {
        int cnt = min(64, deg - base);
        int sr = 0;
        float w = 0.f;
        if (lane < cnt) {
            sr = sorted_src[start + base + lane];
            float v = el[sr] + ern;
            v = (v >= 0.f) ? v : 0.2f * v;
            w = __expf(v);
        }
        int pairs = (cnt + 1) >> 1;
#pragma unroll 4
        for (int it = 0; it < pairs; ++it) {
            int e0 = 2 * it + half_id;
            int   se = __shfl(sr, e0);
            float we = __shfl(w, e0);
            float2 hv = __half22float2(hh2[(long long)se * 32 + l5]);
            a0 += we * hv.x; a1 += we * hv.y;
            ssum += we;
        }
    }

    a0 += __shfl_xor(a0, 32);
    a1 += __shfl_xor(a1, 32);
    ssum += __shfl_xor(ssum, 32);

    if (lane < 32) {
        float inv = (ssum > 0.f) ? 1.f / ssum : 0.f;
        int c = l5 * 2;
        float o0 = a0 * inv + bias[c];
        float o1 = a1 * inv + bias[c + 1];
        if (do_relu) { o0 = fmaxf(o0, 0.f); o1 = fmaxf(o1, 0.f); }
        *reinterpret_cast<float2*>(out + (long long)n * 64 + c) = make_float2(o0, o1);
    }
}

// ============================================================================
// host-side layer driver
// ============================================================================
static void run_layer(const float* x, int Fin, const float* W, const float* al,
                      const float* ar, const float* bias, int H, int D,
                      const int* row_ptr, const int* sorted_src,
                      __half* hh, float* el, float* er, float* xnext, int do_relu,
                      hipStream_t stream) {
    const int gblocks = (N_NODES + 127) / 128;
    const int nblocks = (N_NODES + 3) / 4;
    if (H == 4) {
        gemm_tile<128><<<gblocks, 256, 0, stream>>>(x, W, hh, al, ar, el, er, Fin);
        gat_agg_h4<<<nblocks, 256, 0, stream>>>(row_ptr, sorted_src, el, er, hh,
                                                bias, xnext, do_relu);
    } else {
        gemm_tile<64><<<gblocks, 256, 0, stream>>>(x, W, hh, al, ar, el, er, Fin);
        gat_agg_h1<<<nblocks, 256, 0, stream>>>(row_ptr, sorted_src, el, er, hh,
                                                bias, xnext, do_relu);
    }
}

extern "C" void kernel_launch(void* const* d_in, const int* in_sizes, int n_in,
                              void* d_out, int out_size, void* d_ws, size_t ws_size,
                              hipStream_t stream) {
    const float* feat = (const float*)d_in[0];
    const int*   src  = (const int*)d_in[1];
    const int*   dst  = (const int*)d_in[2];
    const float* W1  = (const float*)d_in[3];
    const float* al1 = (const float*)d_in[4];
    const float* ar1 = (const float*)d_in[5];
    const float* b1  = (const float*)d_in[6];
    const float* W2  = (const float*)d_in[7];
    const float* al2 = (const float*)d_in[8];
    const float* ar2 = (const float*)d_in[9];
    const float* b2  = (const float*)d_in[10];
    const float* W3  = (const float*)d_in[11];
    const float* al3 = (const float*)d_in[12];
    const float* ar3 = (const float*)d_in[13];
    const float* b3  = (const float*)d_in[14];

    // workspace carve-up
    float* ws = (float*)d_ws;
    __half* hh  = (__half*)ws;                          // N*128 halves (in N*64 f32 slot)
    float* xbuf = ws + (long long)N_NODES * 64;         // N*128
    float* el   = xbuf + (long long)N_NODES * 128;      // N*4
    float* er   = el   + (long long)N_NODES * 4;        // N*4
    int* counts     = (int*)(er + (long long)N_NODES * 4);  // N
    int* row_ptr    = counts  + N_NODES;                    // N+1
    int* cursor     = row_ptr + N_NODES + 1;                // N
    int* sorted_src = cursor  + N_NODES;                    // E
    int* bsum       = sorted_src + N_EDGES;                 // 64

    // ---- build CSR once (graph shared by all 3 layers) ----
    const int SB = (N_NODES + 1023) / 1024;   // 49
    zero_counts<<<(N_NODES + 255) / 256, 256, 0, stream>>>(counts);
    hist_kernel<<<(N_EDGES + 255) / 256, 256, 0, stream>>>(dst, counts);
    scan_local<<<SB, 1024, 0, stream>>>(counts, row_ptr, bsum);
    scan_bsums<<<1, 64, 0, stream>>>(bsum, row_ptr, SB);
    scan_add<<<(N_NODES + 255) / 256, 256, 0, stream>>>(row_ptr, bsum, cursor);
    scatter_kernel<<<(N_EDGES + 255) / 256, 256, 0, stream>>>(src, dst, cursor, sorted_src);

    // layer 1: 256 -> 4x32, relu
    run_layer(feat, 256, W1, al1, ar1, b1, 4, 32, row_ptr, sorted_src,
              hh, el, er, xbuf, 1, stream);
    // layer 2: 128 -> 4x32, relu
    run_layer(xbuf, 128, W2, al2, ar2, b2, 4, 32, row_ptr, sorted_src,
              hh, el, er, xbuf, 1, stream);
    // layer 3: 128 -> 1x64, no relu, straight to d_out
    run_layer(xbuf, 128, W3, al3, ar3, b3, 1, 64, row_ptr, sorted_src,
              hh, el, er, (float*)d_out, 0, stream);
}

// Round 10
// 291.811 us; speedup vs baseline: 13.5197x; 1.1491x over previous
//
#include <hip/hip_runtime.h>
#include <hip/hip_fp16.h>
#include <cfloat>

#define N_NODES 50000
#define N_EDGES 800000

typedef _Float16 half8 __attribute__((ext_vector_type(8)));
typedef float f32x4 __attribute__((ext_vector_type(4)));

// ============================================================================
// f32 -> fp16 conversion (float4 -> half4 per thread)
// ============================================================================
__global__ void f2h4(const float* __restrict__ in, __half* __restrict__ out, int n4) {
    int i = blockIdx.x * blockDim.x + threadIdx.x;
    if (i < n4) {
        float4 v = reinterpret_cast<const float4*>(in)[i];
        reinterpret_cast<__half2*>(out)[2 * i + 0] = __floats2half2_rn(v.x, v.y);
        reinterpret_cast<__half2*>(out)[2 * i + 1] = __floats2half2_rn(v.z, v.w);
    }
}

// W[K][BN] f32 -> Wt[BN][K] fp16 (indexed by output; small)
__global__ void wtrans(const float* __restrict__ W, __half* __restrict__ wt, int K, int BN) {
    int i = blockIdx.x * blockDim.x + threadIdx.x;
    if (i < K * BN) {
        int n = i / K, k = i % K;
        wt[i] = __float2half(W[k * BN + n]);
    }
}

// ============================================================================
// MFMA GEMM: h[N,BN] = xh[N,K] @ W (via Wt[BN][K]), fp16 in/out, f32 acc.
// BM=64 rows/block, BK=64, 4 waves x 16-row strips. Fused el/er epilogue.
// Fragment maps (gfx950 16x16x32): A: row=l&15,k=(l>>4)*8+j; B from Wt same;
// C/D: col=l&15, row=(l>>4)*4+reg.
// ============================================================================
template <int BN, int K>
__global__ __launch_bounds__(256)
void gemm_mfma(const __half* __restrict__ xh, const __half* __restrict__ wt,
               __half* __restrict__ hh, const float* __restrict__ al,
               const float* __restrict__ ar, float* __restrict__ el,
               float* __restrict__ er) {
    constexpr int BM = 64, BK = 64;
    constexpr int LDA = BK + 8;              // 72 halves = 144B (9*16B: aligned, 2-way banks)
    constexpr int NT = BN / 16;              // col tiles: 8 | 4
    constexpr int NH = (BN == 128) ? 4 : 1;  // heads
    constexpr int TPH = NT / NH;             // tiles per head
    __shared__ __align__(16) _Float16 As[BM][LDA];
    __shared__ __align__(16) _Float16 Bs[BN][LDA];

    const int t    = threadIdx.x;
    const int lane = t & 63;
    const int w    = t >> 6;
    const int r0   = blockIdx.x * BM;
    const int l15  = lane & 15;
    const int g    = lane >> 4;

    f32x4 acc[NT];
#pragma unroll
    for (int ct = 0; ct < NT; ++ct) acc[ct] = (f32x4){0.f, 0.f, 0.f, 0.f};

    const int arow = t >> 2;           // 0..63
    const int aseg = t & 3;
    const bool aok = (r0 + arow) < N_NODES;
    const int brow = t >> 1;           // 0..127
    const int bseg = t & 1;

    for (int k0 = 0; k0 < K; k0 += BK) {
        // ---- stage A (zero-padded OOB rows) ----
#pragma unroll
        for (int s = 0; s < 2; ++s) {
            int seg = aseg + 4 * s;
            uint4 v = make_uint4(0, 0, 0, 0);
            if (aok) v = *reinterpret_cast<const uint4*>(xh + (long long)(r0 + arow) * K + k0 + seg * 8);
            *reinterpret_cast<uint4*>(&As[arow][seg * 8]) = v;
        }
        // ---- stage B = Wt rows ----
        if (brow < BN) {
#pragma unroll
            for (int s = 0; s < 4; ++s) {
                int seg = bseg + 2 * s;
                uint4 v = *reinterpret_cast<const uint4*>(wt + (long long)brow * K + k0 + seg * 8);
                *reinterpret_cast<uint4*>(&Bs[brow][seg * 8]) = v;
            }
        }
        __syncthreads();

#pragma unroll
        for (int kb = 0; kb < 2; ++kb) {
            half8 a = *reinterpret_cast<const half8*>(&As[w * 16 + l15][kb * 32 + g * 8]);
#pragma unroll
            for (int ct = 0; ct < NT; ++ct) {
                half8 b = *reinterpret_cast<const half8*>(&Bs[ct * 16 + l15][kb * 32 + g * 8]);
                acc[ct] = __builtin_amdgcn_mfma_f32_16x16x32_f16(a, b, acc[ct], 0, 0, 0);
            }
        }
        __syncthreads();
    }

    // ---- epilogue: h store (fp16) + fused el/er ----
    float alv[NT], arv[NT];
#pragma unroll
    for (int ct = 0; ct < NT; ++ct) {
        alv[ct] = al[ct * 16 + l15];
        arv[ct] = ar[ct * 16 + l15];
    }

    float pel[NH][4], per_[NH][4];
#pragma unroll
    for (int hd = 0; hd < NH; ++hd)
#pragma unroll
        for (int b = 0; b < 4; ++b) { pel[hd][b] = 0.f; per_[hd][b] = 0.f; }

#pragma unroll
    for (int ct = 0; ct < NT; ++ct) {
        int hd = ct / TPH;
#pragma unroll
        for (int b = 0; b < 4; ++b) {
            pel[hd][b] += acc[ct][b] * alv[ct];
            per_[hd][b] += acc[ct][b] * arv[ct];
        }
    }
#pragma unroll
    for (int off = 1; off < 16; off <<= 1) {
#pragma unroll
        for (int hd = 0; hd < NH; ++hd)
#pragma unroll
            for (int b = 0; b < 4; ++b) {
                pel[hd][b] += __shfl_xor(pel[hd][b], off);
                per_[hd][b] += __shfl_xor(per_[hd][b], off);
            }
    }

#pragma unroll
    for (int b = 0; b < 4; ++b) {
        int row = r0 + w * 16 + g * 4 + b;
        if (row >= N_NODES) continue;
#pragma unroll
        for (int ct = 0; ct < NT; ++ct)
            hh[(long long)row * BN + ct * 16 + l15] = __float2half(acc[ct][b]);
        if (l15 == 0) {
#pragma unroll
            for (int hd = 0; hd < NH; ++hd) {
                el[row * NH + hd] = pel[hd][b];
                er[row * NH + hd] = per_[hd][b];
            }
        }
    }
}

// ============================================================================
// CSR build (once per call; graph shared by all 3 layers)
// ============================================================================
__global__ void zero_counts(int* __restrict__ counts) {
    int i = blockIdx.x * blockDim.x + threadIdx.x;
    if (i < N_NODES) counts[i] = 0;
}

__global__ void hist_kernel(const int* __restrict__ dst, int* __restrict__ counts) {
    int e = blockIdx.x * blockDim.x + threadIdx.x;
    if (e < N_EDGES) atomicAdd(counts + dst[e], 1);
}

__global__ __launch_bounds__(1024)
void scan_local(const int* __restrict__ counts, int* __restrict__ row_ptr,
                int* __restrict__ bsum) {
    __shared__ int wsums[16];
    const int tid = threadIdx.x, lane = tid & 63, wid = tid >> 6;
    const int i = blockIdx.x * 1024 + tid;
    int v = (i < N_NODES) ? counts[i] : 0;
    int incl = v;
#pragma unroll
    for (int off = 1; off < 64; off <<= 1) {
        int t = __shfl_up(incl, off);
        if (lane >= off) incl += t;
    }
    if (lane == 63) wsums[wid] = incl;
    __syncthreads();
    if (wid == 0) {
        int ws = (lane < 16) ? wsums[lane] : 0;
#pragma unroll
        for (int off = 1; off < 16; off <<= 1) {
            int t = __shfl_up(ws, off);
            if (lane >= off) ws += t;
        }
        if (lane < 16) wsums[lane] = ws;
        if (lane == 15) bsum[blockIdx.x] = ws;
    }
    __syncthreads();
    int woff = (wid > 0) ? wsums[wid - 1] : 0;
    if (i < N_NODES) row_ptr[i] = woff + incl - v;
}

__global__ void scan_bsums(int* __restrict__ bsum, int* __restrict__ row_ptr, int nb) {
    const int lane = threadIdx.x;
    int v = (lane < nb) ? bsum[lane] : 0;
    int incl = v;
#pragma unroll
    for (int off = 1; off < 64; off <<= 1) {
        int t = __shfl_up(incl, off);
        if (lane >= off) incl += t;
    }
    if (lane < nb) bsum[lane] = incl - v;
    if (lane == 63) row_ptr[N_NODES] = incl;
}

__global__ void scan_add(int* __restrict__ row_ptr, const int* __restrict__ bsum,
                         int* __restrict__ cursor) {
    int i = blockIdx.x * blockDim.x + threadIdx.x;
    if (i < N_NODES) {
        int r = row_ptr[i] + bsum[i >> 10];
        row_ptr[i] = r;
        cursor[i]  = r;
    }
}

__global__ void scatter_kernel(const int* __restrict__ src, const int* __restrict__ dst,
                               int* __restrict__ cursor, int* __restrict__ sorted_src) {
    int e = blockIdx.x * blockDim.x + threadIdx.x;
    if (e >= N_EDGES) return;
    int pos = atomicAdd(cursor + dst[e], 1);
    sorted_src[pos] = src[e];
}

// ============================================================================
// Wave-per-node aggregate, 4 heads (F=128), fp16 h, no max pass, 2 edges/iter.
// Output written fp16 (feeds next layer's MFMA GEMM). relu always on here.
// ============================================================================
__global__ __launch_bounds__(256)
void gat_agg_h4(const int* __restrict__ row_ptr, const int* __restrict__ sorted_src,
                const float* __restrict__ el, const float* __restrict__ er,
                const __half* __restrict__ hh, const float* __restrict__ bias,
                __half* __restrict__ out) {
    struct half4 { __half2 a, b; };
    const half4* hh4 = reinterpret_cast<const half4*>(hh);
    const int lane = threadIdx.x & 63;
    const int wid  = threadIdx.x >> 6;
    const int n    = blockIdx.x * 4 + wid;
    if (n >= N_NODES) return;

    const int start = row_ptr[n];
    const int deg   = row_ptr[n + 1] - start;

    const float4 ern = *reinterpret_cast<const float4*>(er + n * 4);

    const int ho = lane >> 4;
    const float eoa = (ho & 2) ? ern.z : ern.x;
    const float eob = (ho & 2) ? ern.w : ern.y;
    const float ero = (ho & 1) ? eob : eoa;

    const int l5      = lane & 31;
    const int hr      = l5 >> 3;
    const int hsh     = hr << 4;
    const int half_id = lane >> 5;

    float a0 = 0.f, a1 = 0.f, a2 = 0.f, a3 = 0.f, ssum = 0.f;

    for (int base = 0; base < deg; base += 64) {
        int cnt = min(64, deg - base);
        int sr = 0;
        if (lane < cnt) sr = sorted_src[start + base + lane];

        float w[4];
#pragma unroll
        for (int k = 0; k < 4; ++k) {
            int ee = (lane & 15) + 16 * k;
            int sk = __shfl(sr, ee);
            float v = el[sk * 4 + ho] + ero;
            v = (v >= 0.f) ? v : 0.2f * v;
            w[k] = (ee < cnt) ? __expf(v) : 0.f;
        }

#pragma unroll
        for (int k = 0; k < 4; ++k) {
            int rem = cnt - 16 * k;
            if (rem > 0) {
                int pairs = (min(rem, 16) + 1) >> 1;
#pragma unroll 4
                for (int it = 0; it < pairs; ++it) {
                    int e0 = 16 * k + 2 * it + half_id;
                    int   se = __shfl(sr, e0);
                    float we = __shfl(w[k], (e0 & 15) | hsh);
                    half4 hv = hh4[(long long)se * 32 + l5];
                    float2 va = __half22float2(hv.a);
                    float2 vb = __half22float2(hv.b);
                    a0 += we * va.x; a1 += we * va.y;
                    a2 += we * vb.x; a3 += we * vb.y;
                    ssum += we;
                }
            }
        }
    }

    a0 += __shfl_xor(a0, 32); a1 += __shfl_xor(a1, 32);
    a2 += __shfl_xor(a2, 32); a3 += __shfl_xor(a3, 32);
    ssum += __shfl_xor(ssum, 32);

    if (lane < 32) {
        float inv = (ssum > 0.f) ? 1.f / ssum : 0.f;
        int c0 = l5 * 4;
        float4 b4 = *reinterpret_cast<const float4*>(bias + c0);
        float o0 = fmaxf(a0 * inv + b4.x, 0.f);
        float o1 = fmaxf(a1 * inv + b4.y, 0.f);
        float o2 = fmaxf(a2 * inv + b4.z, 0.f);
        float o3 = fmaxf(a3 * inv + b4.w, 0.f);
        union { uint2 u; __half2 h[2]; } pk;
        pk.h[0] = __floats2half2_rn(o0, o1);
        pk.h[1] = __floats2half2_rn(o2, o3);
        *reinterpret_cast<uint2*>(out + (long long)n * 128 + c0) = pk.u;
    }
}

// ---- single-head (F=64) variant, fp16 h, 2 edges/iter, f32 out (final) ----
__global__ __launch_bounds__(256)
void gat_agg_h1(const int* __restrict__ row_ptr, const int* __restrict__ sorted_src,
                const float* __restrict__ el, const float* __restrict__ er,
                const __half* __restrict__ hh, const float* __restrict__ bias,
                float* __restrict__ out) {
    const __half2* hh2 = reinterpret_cast<const __half2*>(hh);
    const int lane = threadIdx.x & 63;
    const int wid  = threadIdx.x >> 6;
    const int n    = blockIdx.x * 4 + wid;
    if (n >= N_NODES) return;

    const int start = row_ptr[n];
    const int deg   = row_ptr[n + 1] - start;
    const float ern = er[n];

    const int l5      = lane & 31;
    const int half_id = lane >> 5;

    float a0 = 0.f, a1 = 0.f, ssum = 0.f;

    for (int base = 0; base < deg; base += 64) {
        int cnt = min(64, deg - base);
        int sr = 0;
        float w = 0.f;
        if (lane < cnt) {
            sr = sorted_src[start + base + lane];
            float v = el[sr] + ern;
            v = (v >= 0.f) ? v : 0.2f * v;
            w = __expf(v);
        }
        int pairs = (cnt + 1) >> 1;
#pragma unroll 4
        for (int it = 0; it < pairs; ++it) {
            int e0 = 2 * it + half_id;
            int   se = __shfl(sr, e0);
            float we = __shfl(w, e0);
            float2 hv = __half22float2(hh2[(long long)se * 32 + l5]);
            a0 += we * hv.x; a1 += we * hv.y;
            ssum += we;
        }
    }

    a0 += __shfl_xor(a0, 32);
    a1 += __shfl_xor(a1, 32);
    ssum += __shfl_xor(ssum, 32);

    if (lane < 32) {
        float inv = (ssum > 0.f) ? 1.f / ssum : 0.f;
        int c = l5 * 2;
        float o0 = a0 * inv + bias[c];
        float o1 = a1 * inv + bias[c + 1];
        *reinterpret_cast<float2*>(out + (long long)n * 64 + c) = make_float2(o0, o1);
    }
}

extern "C" void kernel_launch(void* const* d_in, const int* in_sizes, int n_in,
                              void* d_out, int out_size, void* d_ws, size_t ws_size,
                              hipStream_t stream) {
    const float* feat = (const float*)d_in[0];
    const int*   src  = (const int*)d_in[1];
    const int*   dst  = (const int*)d_in[2];
    const float* W1  = (const float*)d_in[3];
    const float* al1 = (const float*)d_in[4];
    const float* ar1 = (const float*)d_in[5];
    const float* b1  = (const float*)d_in[6];
    const float* W2  = (const float*)d_in[7];
    const float* al2 = (const float*)d_in[8];
    const float* ar2 = (const float*)d_in[9];
    const float* b2  = (const float*)d_in[10];
    const float* W3  = (const float*)d_in[11];
    const float* al3 = (const float*)d_in[12];
    const float* ar3 = (const float*)d_in[13];
    const float* b3  = (const float*)d_in[14];

    // workspace carve-up (offsets in f32 units on the base pointer)
    float* ws = (float*)d_ws;
    __half* xh1 = (__half*)ws;                              // N*256 halves = N*128 f32
    __half* xh2 = (__half*)(ws + (long long)N_NODES * 128); // N*128 halves = N*64 f32
    __half* hh  = (__half*)(ws + (long long)N_NODES * 192); // N*128 halves = N*64 f32
    float* el   = ws + (long long)N_NODES * 256;            // N*4
    float* er   = el + (long long)N_NODES * 4;              // N*4
    __half* wt  = (__half*)(er + (long long)N_NODES * 4);   // 256*128 halves = 16384 f32
    int* counts     = (int*)((float*)wt + 16384);           // N
    int* row_ptr    = counts  + N_NODES;                    // N+1
    int* cursor     = row_ptr + N_NODES + 1;                // N
    int* sorted_src = cursor  + N_NODES;                    // E
    int* bsum       = sorted_src + N_EDGES;                 // 64

    // ---- input conversion + CSR build ----
    f2h4<<<(N_NODES * 64 + 255) / 256, 256, 0, stream>>>(feat, xh1, N_NODES * 64);
    const int SB = (N_NODES + 1023) / 1024;   // 49
    zero_counts<<<(N_NODES + 255) / 256, 256, 0, stream>>>(counts);
    hist_kernel<<<(N_EDGES + 255) / 256, 256, 0, stream>>>(dst, counts);
    scan_local<<<SB, 1024, 0, stream>>>(counts, row_ptr, bsum);
    scan_bsums<<<1, 64, 0, stream>>>(bsum, row_ptr, SB);
    scan_add<<<(N_NODES + 255) / 256, 256, 0, stream>>>(row_ptr, bsum, cursor);
    scatter_kernel<<<(N_EDGES + 255) / 256, 256, 0, stream>>>(src, dst, cursor, sorted_src);

    const int gblocks = (N_NODES + 63) / 64;   // 782
    const int nblocks = (N_NODES + 3) / 4;

    // ---- layer 1: 256 -> 4x32, relu ----
    wtrans<<<(256 * 128 + 255) / 256, 256, 0, stream>>>(W1, wt, 256, 128);
    gemm_mfma<128, 256><<<gblocks, 256, 0, stream>>>(xh1, wt, hh, al1, ar1, el, er);
    gat_agg_h4<<<nblocks, 256, 0, stream>>>(row_ptr, sorted_src, el, er, hh, b1, xh2);

    // ---- layer 2: 128 -> 4x32, relu ----
    wtrans<<<(128 * 128 + 255) / 256, 256, 0, stream>>>(W2, wt, 128, 128);
    gemm_mfma<128, 128><<<gblocks, 256, 0, stream>>>(xh2, wt, hh, al2, ar2, el, er);
    gat_agg_h4<<<nblocks, 256, 0, stream>>>(row_ptr, sorted_src, el, er, hh, b2, xh2);

    // ---- layer 3: 128 -> 1x64, no relu, f32 to d_out ----
    wtrans<<<(128 * 64 + 255) / 256, 256, 0, stream>>>(W3, wt, 128, 64);
    gemm_mfma<64, 128><<<gblocks, 256, 0, stream>>>(xh2, wt, hh, al3, ar3, el, er);
    gat_agg_h1<<<nblocks, 256, 0, stream>>>(row_ptr, sorted_src, el, er, hh, b3, (float*)d_out);
}